// Round 13
// baseline (458.082 us; speedup 1.0000x reference)
//
#include <hip/hip_runtime.h>

#define BB 8192
#define DD 1024
#define HH 512
#define LL 64
#define KNN 15
#define NT2 128            // 8192/64 tiles per dim
#define NTILES2 8256       // NT2*(NT2+1)/2
#define NG1T 1024          // G1 64x64 tiles: 128 x 8
#define NBLK2 (NTILES2 + NG1T)   // 9280
#define CHUNK2 (NBLK2 / 8)       // 1160
#define SLOTK 8
#define NEDGE (BB * KNN)
#define NEBLK (NEDGE / 128)

typedef __attribute__((ext_vector_type(4))) float f32x4;
typedef __attribute__((ext_vector_type(8))) short s16x8;
typedef __attribute__((ext_vector_type(8))) unsigned short u16x8;
typedef __attribute__((ext_vector_type(4))) unsigned short u16x4;

typedef s16x8 fragT;

__device__ __forceinline__ unsigned short f2bf(float f) {
  unsigned u = __float_as_uint(f);
  return (unsigned short)((u + 0x7fffu + ((u >> 16) & 1u)) >> 16);  // RNE
}

__device__ __forceinline__ void gload16(const void* g, void* l) {
  __builtin_amdgcn_global_load_lds((const __attribute__((address_space(1))) unsigned int*)g,
                                   (__attribute__((address_space(3))) unsigned int*)l, 16, 0, 0);
}

__device__ __forceinline__ float unpack_d2(unsigned u) {
  _Float16 h = __builtin_bit_cast(_Float16, (unsigned short)(u >> 16));
  return (float)h;
}

__device__ __forceinline__ void ins15(unsigned (&l)[KNN], unsigned u) {
  if (u < l[KNN - 1]) {
    unsigned v = u;
#pragma unroll
    for (int p = 0; p < KNN; ++p) {
      unsigned lo = min(v, l[p]);
      unsigned hi = max(v, l[p]);
      l[p] = lo;
      v = hi;
    }
  }
}

// ---------------- prep: x->bf16+norms + 4 weight transposes ----------------
__global__ void k_prep(const float* __restrict__ x, unsigned short* __restrict__ xb,
                       float* __restrict__ sqx,
                       const float* __restrict__ We1, const float* __restrict__ We2,
                       const float* __restrict__ Wd1, const float* __restrict__ Wd2,
                       unsigned short* __restrict__ Wt1, unsigned short* __restrict__ Wt2,
                       unsigned short* __restrict__ Wt3, unsigned short* __restrict__ Wt4) {
  __shared__ float ps[4];
  __shared__ unsigned short T[64][65];
  int b = blockIdx.x;
  int t = threadIdx.x;
  if (b < BB) {
    f32x4 v = *(const f32x4*)(x + (size_t)b * DD + t * 4);
    u16x4 o;
    float s = 0.f;
#pragma unroll
    for (int j = 0; j < 4; ++j) {
      float f = v[j];
      s += f * f;
      o[j] = f2bf(f);
    }
    *(u16x4*)(xb + (size_t)b * DD + t * 4) = o;
#pragma unroll
    for (int off = 32; off >= 1; off >>= 1) s += __shfl_down(s, off);
    if ((t & 63) == 0) ps[t >> 6] = s;
    __syncthreads();
    if (t == 0) sqx[b] = ps[0] + ps[1] + ps[2] + ps[3];
    return;
  }
  int c = b - BB;
  const float* W;
  unsigned short* Wt;
  int Kd, N, idx;
  if (c < 128)      { W = We1; Wt = Wt1; Kd = DD; N = HH; idx = c; }
  else if (c < 136) { W = We2; Wt = Wt2; Kd = HH; N = LL; idx = c - 128; }
  else if (c < 144) { W = Wd1; Wt = Wt3; Kd = LL; N = HH; idx = c - 136; }
  else              { W = Wd2; Wt = Wt4; Kd = HH; N = DD; idx = c - 144; }
  int nx = Kd >> 6;
  int k0 = (idx % nx) * 64, n0 = (idx / nx) * 64;
  int kr = t >> 4, nc = (t & 15) * 4;
#pragma unroll
  for (int q = 0; q < 4; ++q) {
    int k = kr + q * 16;
    f32x4 v = *(const f32x4*)(W + (size_t)(k0 + k) * N + n0 + nc);
#pragma unroll
    for (int j = 0; j < 4; ++j) T[nc + j][k] = f2bf(v[j]);
  }
  __syncthreads();
#pragma unroll
  for (int q = 0; q < 2; ++q) {
    int s = t + q * 256;
    int n = s >> 3, cc = (s & 7) * 8;
    u16x8 o;
#pragma unroll
    for (int j = 0; j < 8; ++j) o[j] = T[n][cc + j];
    *(u16x8*)(Wt + (size_t)(n0 + n) * Kd + k0 + cc) = o;
  }
}

// ---------------- MFMA-GEMM body (256 thr, 2-phase), for G2..G4 ----------------
template <int NF, int RELU, int FUSE, int STF32, int STBF>
__device__ __forceinline__ void mgemm_body(
    char* LB, int m0, int n0,
    const unsigned short* __restrict__ A, const unsigned short* __restrict__ Wt,
    const float* __restrict__ bias, unsigned short* __restrict__ Cb, float* __restrict__ Cf,
    const float* __restrict__ Xref, float* __restrict__ rec_sum, int N, int Kd) {
  unsigned short* At = (unsigned short*)LB;
  unsigned short* Bt = (unsigned short*)(LB + 16384);
  int t = threadIdx.x;
  int lane = t & 63, w = t >> 6;
  int wr = w >> 1, wc = w & 1;
  int wbase = w * 64;

  const unsigned short* pA[4];
  const unsigned short* pB[NF];
#pragma unroll
  for (int q = 0; q < 4; ++q) {
    int s = q * 256 + t;
    int r = s >> 3, g = s & 7;
    pA[q] = A + (size_t)(m0 + r) * Kd + (g ^ (r & 7)) * 8;
  }
#pragma unroll
  for (int q = 0; q < NF; ++q) {
    int s = q * 256 + t;
    int r = s >> 3, g = s & 7;
    pB[q] = Wt + (size_t)(n0 + r) * Kd + (g ^ (r & 7)) * 8;
  }

  int lrow = lane & 15;
  int klo = (lane >> 4) << 4;
  int sw = (lane & 7) << 4;

  f32x4 acc[4][NF] = {};

  int ksteps = Kd >> 6;
#pragma unroll
  for (int q = 0; q < 4; ++q) { gload16(pA[q], At + (q * 256 + wbase) * 8); pA[q] += 64; }
#pragma unroll
  for (int q = 0; q < NF; ++q) { gload16(pB[q], Bt + (q * 256 + wbase) * 8); pB[q] += 64; }

  for (int kt = 0; kt < ksteps; ++kt) {
    __syncthreads();
    fragT af[2][4], bf[2][NF];
#pragma unroll
    for (int kh = 0; kh < 2; ++kh) {
      int kbyte = ((kh << 6) | klo) ^ sw;
#pragma unroll
      for (int m = 0; m < 4; ++m)
        af[kh][m] = *(const fragT*)((const char*)At + (wr * 64 + m * 16 + lrow) * 128 + kbyte);
#pragma unroll
      for (int n = 0; n < NF; ++n)
        bf[kh][n] = *(const fragT*)((const char*)Bt + (wc * NF * 16 + n * 16 + lrow) * 128 + kbyte);
    }
    __syncthreads();
    if (kt + 1 < ksteps) {
#pragma unroll
      for (int q = 0; q < 4; ++q) { gload16(pA[q], At + (q * 256 + wbase) * 8); pA[q] += 64; }
#pragma unroll
      for (int q = 0; q < NF; ++q) { gload16(pB[q], Bt + (q * 256 + wbase) * 8); pB[q] += 64; }
    }
#pragma unroll
    for (int kh = 0; kh < 2; ++kh)
#pragma unroll
      for (int m = 0; m < 4; ++m)
#pragma unroll
        for (int n = 0; n < NF; ++n)
          acc[m][n] =
              __builtin_amdgcn_mfma_f32_16x16x32_bf16(af[kh][m], bf[kh][n], acc[m][n], 0, 0, 0);
  }

  float local = 0.f;
#pragma unroll
  for (int m = 0; m < 4; ++m) {
    int row0 = m0 + wr * 64 + m * 16 + ((lane >> 4) << 2);
#pragma unroll
    for (int n = 0; n < NF; ++n) {
      int col = n0 + wc * NF * 16 + n * 16 + lrow;
      float bv = bias[col];
      f32x4 a = acc[m][n];
#pragma unroll
      for (int j = 0; j < 4; ++j) {
        float c = a[j] + bv;
        if (RELU) c = fmaxf(c, 0.f);
        if (FUSE) {
          float xv = Xref[(size_t)(row0 + j) * N + col];
          float d = c - xv;
          local = fmaf(d, d, local);
        }
        if (STBF) Cb[(size_t)(row0 + j) * N + col] = f2bf(c);
        if (STF32) Cf[(size_t)(row0 + j) * N + col] = c;
      }
    }
  }
  if (FUSE) {
#pragma unroll
    for (int off = 32; off >= 1; off >>= 1) local += __shfl_down(local, off);
    __shared__ float rs[4];
    if ((t & 63) == 0) rs[t >> 6] = local;
    __syncthreads();
    if (t == 0) atomicAdd(rec_sum, rs[0] + rs[1] + rs[2] + rs[3]);
  }
}

// ---------------- 1-wave 64x64 gram tiles + fused G1, register dataflow ----------------
// No LDS in K-loop: each lane loads its MFMA fragments straight global->VGPR
// (rows lrow+16m, 16B chunk lane>>4), register double-buffered. LDS = scan buffer only.
__global__ __launch_bounds__(64, 3) void k_gram64(
    const unsigned short* __restrict__ xb, const float* __restrict__ sqx,
    unsigned* __restrict__ part,
    const unsigned short* __restrict__ Wt1, const float* __restrict__ be1,
    unsigned short* __restrict__ hb) {
  __shared__ __attribute__((aligned(16))) char LB[8192 + 512];
  float* sql = (float*)(LB + 8192);

  int bid = blockIdx.x;
  int b = (bid & 7) * CHUNK2 + (bid >> 3);  // XCD chunked swizzle (9280 % 8 == 0)
  int lane = threadIdx.x;

  int rt, ct;
  bool isG1, diag;
  const unsigned short* Abase;
  const unsigned short* Bbase;
  if (b < NTILES2) {
    isG1 = false;
    float fr = 128.5f - sqrtf(128.5f * 128.5f - 2.0f * (float)b);
    int r = (int)fr;
    while (128 * (r + 1) - ((r + 1) * r) / 2 <= b) ++r;
    while (128 * r - (r * (r - 1)) / 2 > b) --r;
    rt = r;
    ct = r + (b - (128 * r - (r * (r - 1)) / 2));
    diag = (rt == ct);
    Abase = xb + (size_t)rt * 64 * DD;
    Bbase = xb + (size_t)ct * 64 * DD;
  } else {
    isG1 = true;
    diag = false;
    int gg = b - NTILES2;
    rt = gg >> 3;
    ct = gg & 7;
    Abase = xb + (size_t)rt * 64 * DD;
    Bbase = Wt1 + (size_t)ct * 64 * DD;
  }

  if (!isG1) {
    sql[lane] = sqx[rt * 64 + lane];
    sql[64 + lane] = sqx[ct * 64 + lane];
  }

  int lrow = lane & 15;
  int ch = lane >> 4;  // 16B k-chunk 0..3

  const unsigned short* ap[4];
  const unsigned short* bp[4];
#pragma unroll
  for (int m = 0; m < 4; ++m) {
    ap[m] = Abase + (m * 16 + lrow) * DD + ch * 8;
    bp[m] = Bbase + (m * 16 + lrow) * DD + ch * 8;
  }

  fragT a0[4], b0[4], a1[4], b1[4];
  f32x4 acc[4][4] = {};

#pragma unroll
  for (int m = 0; m < 4; ++m) {
    a0[m] = *(const fragT*)(ap[m]);
    b0[m] = *(const fragT*)(bp[m]);
  }

  for (int kt = 0; kt < 32; kt += 2) {
    int ko = (kt + 1) * 32;
#pragma unroll
    for (int m = 0; m < 4; ++m) {
      a1[m] = *(const fragT*)(ap[m] + ko);
      b1[m] = *(const fragT*)(bp[m] + ko);
    }
#pragma unroll
    for (int n = 0; n < 4; ++n)
#pragma unroll
      for (int m = 0; m < 4; ++m)
        acc[m][n] = __builtin_amdgcn_mfma_f32_16x16x32_bf16(a0[m], b0[n], acc[m][n], 0, 0, 0);
    if (kt + 2 < 32) {
      int ko2 = (kt + 2) * 32;
#pragma unroll
      for (int m = 0; m < 4; ++m) {
        a0[m] = *(const fragT*)(ap[m] + ko2);
        b0[m] = *(const fragT*)(bp[m] + ko2);
      }
    }
#pragma unroll
    for (int n = 0; n < 4; ++n)
#pragma unroll
      for (int m = 0; m < 4; ++m)
        acc[m][n] = __builtin_amdgcn_mfma_f32_16x16x32_bf16(a1[m], b1[n], acc[m][n], 0, 0, 0);
  }

  if (isG1) {
    int n0 = ct * 64;
#pragma unroll
    for (int m = 0; m < 4; ++m)
#pragma unroll
      for (int n = 0; n < 4; ++n) {
        int C = n0 + n * 16 + lrow;
        float bv = be1[C];
        f32x4 a = acc[m][n];
#pragma unroll
        for (int j = 0; j < 4; ++j) {
          int R = rt * 64 + m * 16 + ((lane >> 4) << 2) + j;
          hb[(size_t)R * HH + C] = f2bf(fmaxf(a[j] + bv, 0.f));
        }
      }
    return;
  }

  // ---- write d2 to swizzled f16 Sf [64][64] ----
  char* Sf = LB;
#pragma unroll
  for (int m = 0; m < 4; ++m)
#pragma unroll
    for (int n = 0; n < 4; ++n) {
      int C = n * 16 + lrow;
      float sc = sql[64 + C];
      f32x4 a = acc[m][n];
#pragma unroll
      for (int j = 0; j < 4; ++j) {
        int R = m * 16 + ((lane >> 4) << 2) + j;
        float d2 = fmaxf(sql[R] + sc - 2.f * a[j], 0.f);
        if (diag && R == C) d2 = 60000.f;
        *(_Float16*)(Sf + R * 128 + ((C * 2) ^ ((R & 15) << 3))) = (_Float16)d2;
      }
    }
  asm volatile("s_waitcnt lgkmcnt(0)" ::: "memory");
  __builtin_amdgcn_sched_barrier(0);

  // ---- row-scan: lane owns row `lane` ----
  unsigned rowlist[KNN];
#pragma unroll
  for (int p = 0; p < KNN; ++p) rowlist[p] = 0xFFFFFFFFu;
  {
    int jb = ct * 64;
    const char* rowp = Sf + lane * 128;
    int swr = (lane & 15) << 3;
    for (int cc = 0; cc < 16; ++cc) {
      u16x4 v4 = *(const u16x4*)(rowp + ((cc * 8) ^ swr));
      unsigned u[4];
#pragma unroll
      for (int q = 0; q < 4; ++q) u[q] = ((unsigned)v4[q] << 16) | (unsigned)(jb + cc * 4 + q);
      unsigned m4 = min(min(u[0], u[1]), min(u[2], u[3]));
      if (m4 < rowlist[KNN - 1]) {
#pragma unroll
        for (int q = 0; q < 4; ++q) ins15(rowlist, u[q]);
      }
    }
  }
  {
    size_t base = (size_t)(ct * SLOTK) * BB + rt * 64 + lane;
#pragma unroll
    for (int p = 0; p < SLOTK; ++p) part[base + (size_t)p * BB] = rowlist[p];
  }

  // ---- col-scan: lane owns col `lane` ----
  if (!diag) {
    unsigned collist[KNN];
#pragma unroll
    for (int p = 0; p < KNN; ++p) collist[p] = 0xFFFFFFFFu;
    int ib = rt * 64;
    int c2 = lane * 2;
    for (int rr = 0; rr < 16; ++rr) {
      unsigned u[4];
#pragma unroll
      for (int j = 0; j < 4; ++j) {
        int R = rr * 4 + j;
        unsigned bits = *(const unsigned short*)(Sf + R * 128 + (c2 ^ ((R & 15) << 3)));
        u[j] = (bits << 16) | (unsigned)(ib + R);
      }
      unsigned m4 = min(min(u[0], u[1]), min(u[2], u[3]));
      if (m4 < collist[KNN - 1]) {
#pragma unroll
        for (int j = 0; j < 4; ++j) ins15(collist, u[j]);
      }
    }
    size_t base = (size_t)(rt * SLOTK) * BB + ct * 64 + lane;
#pragma unroll
    for (int p = 0; p < SLOTK; ++p) part[base + (size_t)p * BB] = collist[p];
  }
}

// ---------------- merge bodies ----------------
__device__ __forceinline__ void merge1_body(int gid, const unsigned* __restrict__ part,
                                            unsigned* __restrict__ part2) {
  int s = gid >> 13, i = gid & 8191;
  unsigned l[KNN];
#pragma unroll
  for (int p = 0; p < KNN; ++p) l[p] = 0xFFFFFFFFu;
  for (int b = s * 16; b < s * 16 + 16; ++b) {
    size_t base = (size_t)(b * SLOTK) * BB + i;
    unsigned u = part[base];
    if (u < l[KNN - 1]) {
      ins15(l, u);
      for (int p = 1; p < SLOTK; ++p) {
        u = part[base + (size_t)p * BB];
        if (u >= l[KNN - 1]) break;
        ins15(l, u);
      }
    }
  }
#pragma unroll
  for (int p = 0; p < KNN; ++p) part2[((size_t)(s * KNN + p)) * BB + i] = l[p];
}

__device__ __forceinline__ void merge2_body(int i, const unsigned* __restrict__ part2,
                                            float* __restrict__ knn_d2, int* __restrict__ knn_idx,
                                            int* __restrict__ xmax_bits) {
  unsigned l[KNN];
#pragma unroll
  for (int p = 0; p < KNN; ++p) l[p] = 0xFFFFFFFFu;
  for (int q = 0; q < 8; ++q) {
    size_t base = (size_t)(q * KNN) * BB + i;
    unsigned u = part2[base];
    if (u < l[KNN - 1]) {
      ins15(l, u);
      for (int p = 1; p < KNN; ++p) {
        u = part2[base + (size_t)p * BB];
        if (u >= l[KNN - 1]) break;
        ins15(l, u);
      }
    }
  }
  float mx = 0.f;
#pragma unroll
  for (int p = 0; p < KNN; ++p) {
    unsigned u = l[p];
    float d = fmaxf(unpack_d2(u), 0.f);
    mx = fmaxf(mx, d);
    knn_d2[(size_t)i * KNN + p] = d;
    knn_idx[(size_t)i * KNN + p] = (int)(u & 0xFFFFu);
  }
  int t = threadIdx.x;
#pragma unroll
  for (int off = 32; off >= 1; off >>= 1) mx = fmaxf(mx, __shfl_down(mx, off));
  __shared__ float rm[4];
  if ((t & 63) == 0) rm[t >> 6] = mx;
  __syncthreads();
  if (t == 0) {
    float mb = fmaxf(fmaxf(rm[0], rm[1]), fmaxf(rm[2], rm[3]));
    atomicMax(xmax_bits, __float_as_int(mb));
  }
}

// ---------------- edge body: zd2 + reciprocity + partial sums ----------------
__device__ __forceinline__ void edge_body(int eb, const float* __restrict__ z,
                                          const int* __restrict__ knn_idx,
                                          const float* __restrict__ knn_d2,
                                          float* __restrict__ pzz, float* __restrict__ pxx,
                                          float* __restrict__ pxz, float* __restrict__ pcnt,
                                          float* __restrict__ pzm) {
  int t = threadIdx.x;
  int g = t >> 4, L = t & 15;
  int lane = t & 63;
  float szz = 0.f, sxx = 0.f, sxz = 0.f, scnt = 0.f, zm = 0.f;
#pragma unroll
  for (int pass = 0; pass < 8; ++pass) {
    int e = eb * 128 + pass * 16 + g;
    int i = e / KNN;
    int j = knn_idx[e];
    f32x4 zi = *(const f32x4*)(z + (size_t)i * LL + L * 4);
    f32x4 zj = *(const f32x4*)(z + (size_t)j * LL + L * 4);
    float v = 0.f;
#pragma unroll
    for (int d = 0; d < 4; ++d) {
      float df = zi[d] - zj[d];
      v = fmaf(df, df, v);
    }
    v += __shfl_down(v, 8);
    v += __shfl_down(v, 4);
    v += __shfl_down(v, 2);
    v += __shfl_down(v, 1);
    int cand = (L < KNN) ? knn_idx[(size_t)j * KNN + L] : -1;
    unsigned long long ball = __ballot(cand == i);
    unsigned recip = (unsigned)(ball >> (lane & 48)) & 0xFFFFu;
    if (L == 0) {
      float w = recip ? 1.f : 2.f;
      float xd2 = knn_d2[e];
      szz = fmaf(w, v, szz);
      sxx = fmaf(w, xd2, sxx);
      sxz = fmaf(w, sqrtf(v * xd2), sxz);
      scnt += w;
      zm = fmaxf(zm, v);
    }
  }
#pragma unroll
  for (int off = 32; off >= 1; off >>= 1) {
    szz += __shfl_down(szz, off);
    sxx += __shfl_down(sxx, off);
    sxz += __shfl_down(sxz, off);
    scnt += __shfl_down(scnt, off);
    zm = fmaxf(zm, __shfl_down(zm, off));
  }
  __shared__ float r[5][4];
  int w4 = t >> 6;
  if (lane == 0) {
    r[0][w4] = szz; r[1][w4] = sxx; r[2][w4] = sxz; r[3][w4] = scnt; r[4][w4] = zm;
  }
  __syncthreads();
  if (t == 0) {
    pzz[eb] = r[0][0] + r[0][1] + r[0][2] + r[0][3];
    pxx[eb] = r[1][0] + r[1][1] + r[1][2] + r[1][3];
    pxz[eb] = r[2][0] + r[2][1] + r[2][2] + r[2][3];
    pcnt[eb] = r[3][0] + r[3][1] + r[3][2] + r[3][3];
    pzm[eb] = fmaxf(fmaxf(r[4][0], r[4][1]), fmaxf(r[4][2], r[4][3]));
  }
}

// ---------------- fused tails ----------------
// tail2: G2 (64 blocks) + merge1 (256 blocks)
__global__ __launch_bounds__(256) void k_tail2(
    const unsigned short* __restrict__ hb, const unsigned short* __restrict__ Wt2,
    const float* __restrict__ be2, unsigned short* __restrict__ zb, float* __restrict__ z,
    const unsigned* __restrict__ part, unsigned* __restrict__ part2) {
  __shared__ __attribute__((aligned(16))) char LB[16384 + 8192];
  int bid = blockIdx.x;
  if (bid < 64) {
    mgemm_body<2, 0, 0, 1, 1>(LB, bid * 128, 0, hb, Wt2, be2, zb, z, nullptr, nullptr, LL, HH);
  } else {
    merge1_body((bid - 64) * 256 + threadIdx.x, part, part2);
  }
}

// tail3: G3 (256 blocks) + merge2 (32 blocks)
__global__ __launch_bounds__(256) void k_tail3(
    const unsigned short* __restrict__ zb, const unsigned short* __restrict__ Wt3,
    const float* __restrict__ bd1, unsigned short* __restrict__ h2b,
    const unsigned* __restrict__ part2, float* __restrict__ knn_d2, int* __restrict__ knn_idx,
    int* __restrict__ xmax_bits) {
  __shared__ __attribute__((aligned(16))) char LB[16384 + 16384];
  int bid = blockIdx.x;
  if (bid < 256) {
    mgemm_body<4, 1, 0, 0, 1>(LB, (bid >> 2) * 128, (bid & 3) * 128, zb, Wt3, bd1, h2b, nullptr,
                              nullptr, nullptr, HH, LL);
  } else {
    merge2_body((bid - 256) * 256 + threadIdx.x, part2, knn_d2, knn_idx, xmax_bits);
  }
}

// tail4: G4 (512 blocks) + edge (960 blocks)
__global__ __launch_bounds__(256) void k_tail4(
    const unsigned short* __restrict__ h2b, const unsigned short* __restrict__ Wt4,
    const float* __restrict__ bd2, const float* __restrict__ x, float* __restrict__ rec_sum,
    const float* __restrict__ z, const int* __restrict__ knn_idx,
    const float* __restrict__ knn_d2, float* __restrict__ pzz, float* __restrict__ pxx,
    float* __restrict__ pxz, float* __restrict__ pcnt, float* __restrict__ pzm) {
  __shared__ __attribute__((aligned(16))) char LB[16384 + 16384];
  int bid = blockIdx.x;
  if (bid < 512) {
    mgemm_body<4, 0, 1, 0, 0>(LB, (bid >> 3) * 128, (bid & 7) * 128, h2b, Wt4, bd2, nullptr,
                              nullptr, x, rec_sum, DD, HH);
  } else {
    edge_body(bid - 512, z, knn_idx, knn_d2, pzz, pxx, pxz, pcnt, pzm);
  }
}

// ---------------- final: reduce partials, assemble scalar loss ----------------
__global__ void k_final(const float* __restrict__ pzz, const float* __restrict__ pxx,
                        const float* __restrict__ pxz, const float* __restrict__ pcnt,
                        const float* __restrict__ pzm, const int* __restrict__ xmax_bits,
                        const float* __restrict__ rec_sum, float* __restrict__ out) {
  int t = threadIdx.x;
  float szz = 0.f, sxx = 0.f, sxz = 0.f, scnt = 0.f, zm = 0.f;
  for (int bb = t; bb < NEBLK; bb += 256) {
    szz += pzz[bb];
    sxx += pxx[bb];
    sxz += pxz[bb];
    scnt += pcnt[bb];
    zm = fmaxf(zm, pzm[bb]);
  }
#pragma unroll
  for (int off = 32; off >= 1; off >>= 1) {
    szz += __shfl_down(szz, off);
    sxx += __shfl_down(sxx, off);
    sxz += __shfl_down(sxz, off);
    scnt += __shfl_down(scnt, off);
    zm = fmaxf(zm, __shfl_down(zm, off));
  }
  __shared__ float r[5][4];
  int w4 = t >> 6;
  if ((t & 63) == 0) {
    r[0][w4] = szz; r[1][w4] = sxx; r[2][w4] = sxz; r[3][w4] = scnt; r[4][w4] = zm;
  }
  __syncthreads();
  if (t == 0) {
    float SZZ = r[0][0] + r[0][1] + r[0][2] + r[0][3];
    float SXX = r[1][0] + r[1][1] + r[1][2] + r[1][3];
    float SXZ = r[2][0] + r[2][1] + r[2][2] + r[2][3];
    float CNT = r[3][0] + r[3][1] + r[3][2] + r[3][3];
    float ZM = fmaxf(fmaxf(r[4][0], r[4][1]), fmaxf(r[4][2], r[4][3]));
    float xmax = __int_as_float(*xmax_bits);
    float a = 1.f / (sqrtf(ZM) + 1e-8f);
    float bq = 1.f / (sqrtf(xmax) + 1e-8f);
    float loss = (a * a * SZZ + bq * bq * SXX - 2.f * a * bq * SXZ) / CNT;
    out[0] = rec_sum[0] * (1.f / 8388608.f) + loss;
  }
}

extern "C" void kernel_launch(void* const* d_in, const int* in_sizes, int n_in,
                              void* d_out, int out_size, void* d_ws, size_t ws_size,
                              hipStream_t stream) {
  const float* x = (const float*)d_in[0];
  const float* We1 = (const float*)d_in[1];
  const float* be1 = (const float*)d_in[2];
  const float* We2 = (const float*)d_in[3];
  const float* be2 = (const float*)d_in[4];
  const float* Wd1 = (const float*)d_in[5];
  const float* bd1 = (const float*)d_in[6];
  const float* Wd2 = (const float*)d_in[7];
  const float* bd2 = (const float*)d_in[8];

  char* ws = (char*)d_ws;
  size_t off = 0;
  auto alloc = [&](size_t bytes) {
    void* p = ws + off;
    off += (bytes + 255) & ~(size_t)255;
    return p;
  };
  unsigned short* xb = (unsigned short*)alloc((size_t)BB * DD * 2);
  unsigned short* hb = (unsigned short*)alloc((size_t)BB * HH * 2);
  unsigned short* zb = (unsigned short*)alloc((size_t)BB * LL * 2);
  unsigned short* h2b = (unsigned short*)alloc((size_t)BB * HH * 2);
  float* z = (float*)alloc((size_t)BB * LL * 4);
  float* sqx = (float*)alloc((size_t)BB * 4);
  unsigned short* Wt1 = (unsigned short*)alloc((size_t)HH * DD * 2);
  unsigned short* Wt2 = (unsigned short*)alloc((size_t)LL * HH * 2);
  unsigned short* Wt3 = (unsigned short*)alloc((size_t)HH * LL * 2);
  unsigned short* Wt4 = (unsigned short*)alloc((size_t)DD * HH * 2);
  unsigned* part = (unsigned*)alloc((size_t)NT2 * SLOTK * BB * 4);  // 33.5MB
  unsigned* part2 = (unsigned*)alloc((size_t)8 * KNN * BB * 4);     // 3.9MB
  float* knn_d2 = (float*)alloc((size_t)BB * KNN * 4);
  int* knn_idx = (int*)alloc((size_t)BB * KNN * 4);
  float* pzz = (float*)alloc(NEBLK * 4);
  float* pxx = (float*)alloc(NEBLK * 4);
  float* pxz = (float*)alloc(NEBLK * 4);
  float* pcnt = (float*)alloc(NEBLK * 4);
  float* pzm = (float*)alloc(NEBLK * 4);
  float* scal = (float*)alloc(64);
  float* rec_sum = scal + 0;
  int* xmax_bits = (int*)(scal + 1);

  hipMemsetAsync(scal, 0, 64, stream);

  k_prep<<<BB + 272, 256, 0, stream>>>(x, xb, sqx, We1, We2, Wd1, Wd2, Wt1, Wt2, Wt3, Wt4);

  k_gram64<<<NBLK2, 64, 0, stream>>>(xb, sqx, part, Wt1, be1, hb);

  k_tail2<<<64 + 256, 256, 0, stream>>>(hb, Wt2, be2, zb, z, part, part2);
  k_tail3<<<256 + 32, 256, 0, stream>>>(zb, Wt3, bd1, h2b, part2, knn_d2, knn_idx, xmax_bits);
  k_tail4<<<512 + NEBLK, 256, 0, stream>>>(h2b, Wt4, bd2, x, rec_sum, z, knn_idx, knn_d2,
                                           pzz, pxx, pxz, pcnt, pzm);
  k_final<<<1, 256, 0, stream>>>(pzz, pxx, pxz, pcnt, pzm, xmax_bits, rec_sum, (float*)d_out);
}

// Round 14
// 349.680 us; speedup vs baseline: 1.3100x; 1.3100x over previous
//
#include <hip/hip_runtime.h>

#define BB 8192
#define DD 1024
#define HH 512
#define LL 64
#define KNN 15
#define NT 64            // 8192/128 tiles per dim
#define NTILES 2080      // NT*(NT+1)/2
#define NG1 256          // fused G1 blocks
#define NEDGE (BB * KNN)
#define NEBLK (NEDGE / 128)  // 960 edge blocks

typedef __attribute__((ext_vector_type(4))) float f32x4;
typedef __attribute__((ext_vector_type(8))) short s16x8;
typedef __attribute__((ext_vector_type(8))) unsigned short u16x8;
typedef __attribute__((ext_vector_type(4))) unsigned short u16x4;
typedef __attribute__((ext_vector_type(4))) _Float16 f16x4;

typedef s16x8 fragT;

__device__ __forceinline__ unsigned short f2bf(float f) {
  unsigned u = __float_as_uint(f);
  return (unsigned short)((u + 0x7fffu + ((u >> 16) & 1u)) >> 16);  // RNE
}

__device__ __forceinline__ void gload16(const void* g, void* l) {
  __builtin_amdgcn_global_load_lds((const __attribute__((address_space(1))) unsigned int*)g,
                                   (__attribute__((address_space(3))) unsigned int*)l, 16, 0, 0);
}

__device__ __forceinline__ float unpack_d2(unsigned u) {
  _Float16 h = __builtin_bit_cast(_Float16, (unsigned short)(u >> 16));
  return (float)h;
}

// sorted ascending top-15 insert via min/max network
__device__ __forceinline__ void ins15(unsigned (&l)[KNN], unsigned u) {
  if (u < l[KNN - 1]) {
    unsigned v = u;
#pragma unroll
    for (int p = 0; p < KNN; ++p) {
      unsigned lo = min(v, l[p]);
      unsigned hi = max(v, l[p]);
      l[p] = lo;
      v = hi;
    }
  }
}

// ---------------- prep: x->bf16+norms (blocks 0..8191) + 4 weight transposes ----------------
__global__ void k_prep(const float* __restrict__ x, unsigned short* __restrict__ xb,
                       float* __restrict__ sqx,
                       const float* __restrict__ We1, const float* __restrict__ We2,
                       const float* __restrict__ Wd1, const float* __restrict__ Wd2,
                       unsigned short* __restrict__ Wt1, unsigned short* __restrict__ Wt2,
                       unsigned short* __restrict__ Wt3, unsigned short* __restrict__ Wt4) {
  __shared__ float ps[4];
  __shared__ unsigned short T[64][65];
  int b = blockIdx.x;
  int t = threadIdx.x;
  if (b < BB) {
    f32x4 v = *(const f32x4*)(x + (size_t)b * DD + t * 4);
    u16x4 o;
    float s = 0.f;
#pragma unroll
    for (int j = 0; j < 4; ++j) {
      float f = v[j];
      s += f * f;
      o[j] = f2bf(f);
    }
    *(u16x4*)(xb + (size_t)b * DD + t * 4) = o;
#pragma unroll
    for (int off = 32; off >= 1; off >>= 1) s += __shfl_down(s, off);
    if ((t & 63) == 0) ps[t >> 6] = s;
    __syncthreads();
    if (t == 0) sqx[b] = ps[0] + ps[1] + ps[2] + ps[3];
    return;
  }
  int c = b - BB;
  const float* W;
  unsigned short* Wt;
  int Kd, N, idx;
  if (c < 128)      { W = We1; Wt = Wt1; Kd = DD; N = HH; idx = c; }
  else if (c < 136) { W = We2; Wt = Wt2; Kd = HH; N = LL; idx = c - 128; }
  else if (c < 144) { W = Wd1; Wt = Wt3; Kd = LL; N = HH; idx = c - 136; }
  else              { W = Wd2; Wt = Wt4; Kd = HH; N = DD; idx = c - 144; }
  int nx = Kd >> 6;
  int k0 = (idx % nx) * 64, n0 = (idx / nx) * 64;
  int kr = t >> 4, nc = (t & 15) * 4;
#pragma unroll
  for (int q = 0; q < 4; ++q) {
    int k = kr + q * 16;
    f32x4 v = *(const f32x4*)(W + (size_t)(k0 + k) * N + n0 + nc);
#pragma unroll
    for (int j = 0; j < 4; ++j) T[nc + j][k] = f2bf(v[j]);
  }
  __syncthreads();
#pragma unroll
  for (int q = 0; q < 2; ++q) {
    int s = t + q * 256;
    int n = s >> 3, cc = (s & 7) * 8;
    u16x8 o;
#pragma unroll
    for (int j = 0; j < 8; ++j) o[j] = T[n][cc + j];
    *(u16x8*)(Wt + (size_t)(n0 + n) * Kd + k0 + cc) = o;
  }
}

// ---------------- MFMA-GEMM body (256 thr, 2-phase) for G2..G4 ----------------
template <int NF, int RELU, int FUSE, int STF32, int STBF>
__device__ __forceinline__ void mgemm_body(
    char* LB, int m0, int n0,
    const unsigned short* __restrict__ A, const unsigned short* __restrict__ Wt,
    const float* __restrict__ bias, unsigned short* __restrict__ Cb, float* __restrict__ Cf,
    const float* __restrict__ Xref, float* __restrict__ rec_sum, int N, int Kd) {
  unsigned short* At = (unsigned short*)LB;
  unsigned short* Bt = (unsigned short*)(LB + 16384);
  int t = threadIdx.x;
  int lane = t & 63, w = t >> 6;
  int wr = w >> 1, wc = w & 1;
  int wbase = w * 64;

  const unsigned short* pA[4];
  const unsigned short* pB[NF];
#pragma unroll
  for (int q = 0; q < 4; ++q) {
    int s = q * 256 + t;
    int r = s >> 3, g = s & 7;
    pA[q] = A + (size_t)(m0 + r) * Kd + (g ^ (r & 7)) * 8;
  }
#pragma unroll
  for (int q = 0; q < NF; ++q) {
    int s = q * 256 + t;
    int r = s >> 3, g = s & 7;
    pB[q] = Wt + (size_t)(n0 + r) * Kd + (g ^ (r & 7)) * 8;
  }

  int lrow = lane & 15;
  int klo = (lane >> 4) << 4;
  int sw = (lane & 7) << 4;

  f32x4 acc[4][NF] = {};

  int ksteps = Kd >> 6;
#pragma unroll
  for (int q = 0; q < 4; ++q) { gload16(pA[q], At + (q * 256 + wbase) * 8); pA[q] += 64; }
#pragma unroll
  for (int q = 0; q < NF; ++q) { gload16(pB[q], Bt + (q * 256 + wbase) * 8); pB[q] += 64; }

  for (int kt = 0; kt < ksteps; ++kt) {
    __syncthreads();
    fragT af[2][4], bf[2][NF];
#pragma unroll
    for (int kh = 0; kh < 2; ++kh) {
      int kbyte = ((kh << 6) | klo) ^ sw;
#pragma unroll
      for (int m = 0; m < 4; ++m)
        af[kh][m] = *(const fragT*)((const char*)At + (wr * 64 + m * 16 + lrow) * 128 + kbyte);
#pragma unroll
      for (int n = 0; n < NF; ++n)
        bf[kh][n] = *(const fragT*)((const char*)Bt + (wc * NF * 16 + n * 16 + lrow) * 128 + kbyte);
    }
    __syncthreads();
    if (kt + 1 < ksteps) {
#pragma unroll
      for (int q = 0; q < 4; ++q) { gload16(pA[q], At + (q * 256 + wbase) * 8); pA[q] += 64; }
#pragma unroll
      for (int q = 0; q < NF; ++q) { gload16(pB[q], Bt + (q * 256 + wbase) * 8); pB[q] += 64; }
    }
#pragma unroll
    for (int kh = 0; kh < 2; ++kh)
#pragma unroll
      for (int m = 0; m < 4; ++m)
#pragma unroll
        for (int n = 0; n < NF; ++n)
          acc[m][n] =
              __builtin_amdgcn_mfma_f32_16x16x32_bf16(af[kh][m], bf[kh][n], acc[m][n], 0, 0, 0);
  }

  float local = 0.f;
#pragma unroll
  for (int m = 0; m < 4; ++m) {
    int row0 = m0 + wr * 64 + m * 16 + ((lane >> 4) << 2);
#pragma unroll
    for (int n = 0; n < NF; ++n) {
      int col = n0 + wc * NF * 16 + n * 16 + lrow;
      float bv = bias[col];
      f32x4 a = acc[m][n];
#pragma unroll
      for (int j = 0; j < 4; ++j) {
        float c = a[j] + bv;
        if (RELU) c = fmaxf(c, 0.f);
        if (FUSE) {
          float xv = Xref[(size_t)(row0 + j) * N + col];
          float d = c - xv;
          local = fmaf(d, d, local);
        }
        if (STBF) Cb[(size_t)(row0 + j) * N + col] = f2bf(c);
        if (STF32) Cf[(size_t)(row0 + j) * N + col] = c;
      }
    }
  }
  if (FUSE) {
#pragma unroll
    for (int off = 32; off >= 1; off >>= 1) local += __shfl_down(local, off);
    __shared__ float rs[4];
    if ((t & 63) == 0) rs[t >> 6] = local;
    __syncthreads();
    if (t == 0) atomicAdd(rec_sum, rs[0] + rs[1] + rs[2] + rs[3]);
  }
}

template <int NF, int RELU, int FUSE, int STF32, int STBF>
__global__ __launch_bounds__(256) void k_mgemm(
    const unsigned short* __restrict__ A, const unsigned short* __restrict__ Wt,
    const float* __restrict__ bias, unsigned short* __restrict__ Cb, float* __restrict__ Cf,
    const float* __restrict__ Xref, float* __restrict__ rec_sum, int N, int Kd) {
  __shared__ __attribute__((aligned(16))) char LB[16384 + NF * 32 * 128];
  mgemm_body<NF, RELU, FUSE, STF32, STBF>(LB, blockIdx.y * 128, blockIdx.x * (NF * 32),
                                          A, Wt, bias, Cb, Cf, Xref, rec_sum, N, Kd);
}

// ---------------- fat kernel: G1 (256 blocks) + Gram/top-15, 8 waves/block ----------------
// 512 thr: wave w -> 32x64 sub-tile (wr=w&3, wc=w>>2). acc 32 AGPR/wave -> <=128 reg tier
// -> 4 waves/SIMD = 16 waves/CU (2 blocks). Same LDS/swizzle/schedule as the r11 kernel.
__global__ __launch_bounds__(512, 4) void k_gram_topk(
    const unsigned short* __restrict__ xb, const float* __restrict__ sqx,
    unsigned* __restrict__ part,
    const unsigned short* __restrict__ Wt1, const float* __restrict__ be1,
    unsigned short* __restrict__ hb) {
  __shared__ __attribute__((aligned(16))) char LB[33792];
  unsigned short* At = (unsigned short*)LB;
  unsigned short* Bt = (unsigned short*)(LB + 16384);
  char* Sf = LB;                                  // scan phase (overlays At)
  unsigned* scratch = (unsigned*)(LB + 16384);    // scan phase (overlays Bt)
  float* sqr = (float*)(LB + 32768);
  float* sqc = (float*)(LB + 33280);

  int bid0 = blockIdx.x;
  int t = threadIdx.x;
  int lane = t & 63, w = t >> 6;
  int wr = w & 3, wc = w >> 2;
  int lrow = lane & 15;

  int rt, ct;
  bool isG1, diag;
  if (bid0 < NG1) {
    isG1 = true;
    diag = false;
    rt = bid0 >> 2;   // 64 row-blocks of 128
    ct = bid0 & 3;    // 4 col-blocks of 128 (HH=512)
  } else {
    isG1 = false;
    int g = bid0 - NG1;
    int k = g & 7, m = g >> 3;
    int nA = 250 - 16 * k;
    int b, mm;
    if (m < nA) { b = k; mm = m; }
    else        { b = 15 - k; mm = m - nA; }
    int ctl, j;
    if (mm < 6) {
      if (mm < 1)      { ctl = 0; j = 0; }
      else if (mm < 3) { ctl = 1; j = mm - 1; }
      else             { ctl = 2; j = mm - 3; }
    } else {
      ctl = 3 + ((mm - 6) >> 2);
      j = (mm - 6) & 3;
    }
    rt = 4 * b + j;
    ct = 4 * b + ctl;
    diag = (rt == ct);
  }
  int r0 = rt * 128;
  const unsigned short* Abase = xb + (size_t)r0 * DD;
  const unsigned short* Bbase =
      isG1 ? (Wt1 + (size_t)ct * 128 * DD) : (xb + (size_t)ct * 128 * DD);

  if (!isG1 && t < 128) {
    sqr[t] = sqx[r0 + t];
    sqc[t] = sqx[ct * 128 + t];
  }

  // staging: 1024 slots x 16B per buffer; thread t -> slots {t, t+512}
  const unsigned short* pA[2];
  const unsigned short* pB[2];
  int dsts[2];
#pragma unroll
  for (int q = 0; q < 2; ++q) {
    int s = q * 512 + t;
    int r = s >> 3, g2 = s & 7;
    int ksh = (g2 ^ (r & 7)) * 8;
    pA[q] = Abase + (size_t)r * DD + ksh;
    pB[q] = Bbase + (size_t)r * DD + ksh;
    dsts[q] = s * 8;
  }

  int klo = (lane >> 4) << 4;
  int sw = (lane & 7) << 4;

  f32x4 acc[2][4] = {};

#pragma unroll
  for (int q = 0; q < 2; ++q) {
    gload16(pA[q], At + dsts[q]); pA[q] += 64;
    gload16(pB[q], Bt + dsts[q]); pB[q] += 64;
  }

  for (int kt = 0; kt < 16; ++kt) {
    __syncthreads();  // stage(kt) landed
    fragT af[2][2], bf[2][4];
#pragma unroll
    for (int kh = 0; kh < 2; ++kh) {
      int kbyte = ((kh << 6) | klo) ^ sw;
#pragma unroll
      for (int m = 0; m < 2; ++m)
        af[kh][m] = *(const fragT*)((const char*)At + (wr * 32 + m * 16 + lrow) * 128 + kbyte);
#pragma unroll
      for (int n = 0; n < 4; ++n)
        bf[kh][n] = *(const fragT*)((const char*)Bt + (wc * 64 + n * 16 + lrow) * 128 + kbyte);
    }
    __syncthreads();  // all waves consumed LDS
    if (kt + 1 < 16) {
#pragma unroll
      for (int q = 0; q < 2; ++q) {
        gload16(pA[q], At + dsts[q]); pA[q] += 64;
        gload16(pB[q], Bt + dsts[q]); pB[q] += 64;
      }
    }
#pragma unroll
    for (int kh = 0; kh < 2; ++kh)
#pragma unroll
      for (int m = 0; m < 2; ++m)
#pragma unroll
        for (int n = 0; n < 4; ++n)
          acc[m][n] =
              __builtin_amdgcn_mfma_f32_16x16x32_bf16(af[kh][m], bf[kh][n], acc[m][n], 0, 0, 0);
  }

  if (isG1) {
    int n0 = ct * 128 + wc * 64;
#pragma unroll
    for (int m = 0; m < 2; ++m)
#pragma unroll
      for (int n = 0; n < 4; ++n) {
        int C = n0 + n * 16 + lrow;
        float bv = be1[C];
        f32x4 a = acc[m][n];
#pragma unroll
        for (int j = 0; j < 4; ++j) {
          int R = r0 + wr * 32 + m * 16 + ((lane >> 4) << 2) + j;
          hb[(size_t)R * HH + C] = f2bf(fmaxf(a[j] + bv, 0.f));
        }
      }
    return;
  }

  unsigned rowlist[KNN];
#pragma unroll
  for (int p = 0; p < KNN; ++p) rowlist[p] = 0xFFFFFFFFu;

  int scanrow = t & 127, side = (t >> 7) & 1;

#pragma unroll
  for (int nh = 0; nh < 2; ++nh) {
    // write d2 half-tile (cols nh*64..+63) to swizzled f16 Sf
    if (wc == nh) {
#pragma unroll
      for (int m = 0; m < 2; ++m) {
        int row0 = wr * 32 + m * 16 + ((lane >> 4) << 2);
        f32x4 sq4 = *(const f32x4*)&sqr[row0];
#pragma unroll
        for (int n = 0; n < 4; ++n) {
          int colL = n * 16 + lrow;
          float sc = sqc[nh * 64 + colL];
          f32x4 a = acc[m][n];
          f16x4 hv;
#pragma unroll
          for (int j = 0; j < 4; ++j) {
            float d2 = fmaxf(sq4[j] + sc - 2.f * a[j], 0.f);
            if (diag && (row0 + j == nh * 64 + colL)) d2 = 60000.f;
            hv[j] = (_Float16)d2;
          }
          *(f16x4*)(Sf + colL * 256 + ((row0 * 2) ^ ((colL & 31) << 3))) = hv;
        }
      }
    }
    __syncthreads();
    // row-scan: threads <256, 2 per row, 32 cols each; chunk-of-4 min prefilter
    if (t < 256) {
      int cbase = side * 32;
      int jbase = ct * 128 + nh * 64;
      for (int cc = 0; cc < 32; cc += 4) {
        unsigned u[4];
#pragma unroll
        for (int q = 0; q < 4; ++q) {
          int colL = cbase + cc + q;
          unsigned bits = *(const unsigned short*)(Sf + colL * 256 +
                                                   ((scanrow * 2) ^ ((colL & 31) << 3)));
          u[q] = (bits << 16) | (unsigned)(jbase + colL);
        }
        unsigned m4 = min(min(u[0], u[1]), min(u[2], u[3]));
        if (m4 < rowlist[KNN - 1]) {
#pragma unroll
          for (int q = 0; q < 4; ++q) ins15(rowlist, u[q]);
        }
      }
    }
    // col-scan: threads <256, c = t&63, seg = t>>6 (4 segs x 32 rows)
    if (!diag) {
      unsigned collist[KNN];
#pragma unroll
      for (int p = 0; p < KNN; ++p) collist[p] = 0xFFFFFFFFu;
      if (t < 256) {
        int c = t & 63, seg = t >> 6;
        for (int rq = 0; rq < 8; ++rq) {
          int r = seg * 32 + rq * 4;
          u16x4 v4 = *(const u16x4*)(Sf + c * 256 + ((r * 2) ^ ((c & 31) << 3)));
          unsigned u[4];
#pragma unroll
          for (int jj = 0; jj < 4; ++jj)
            u[jj] = ((unsigned)v4[jj] << 16) | (unsigned)(r0 + r + jj);
          unsigned m4 = min(min(u[0], u[1]), min(u[2], u[3]));
          if (m4 < collist[KNN - 1]) {
#pragma unroll
            for (int jj = 0; jj < 4; ++jj) ins15(collist, u[jj]);
          }
        }
      }
      __syncthreads();
      if (t < 256) {
        int c = t & 63, seg = t >> 6;
#pragma unroll
        for (int p = 0; p < KNN; ++p) scratch[(c * 4 + seg) * KNN + p] = collist[p];
      }
      __syncthreads();
      if (t < 64) {
        unsigned fin[KNN];
#pragma unroll
        for (int p = 0; p < KNN; ++p) fin[p] = 0xFFFFFFFFu;
        for (int s = 0; s < 4; ++s)
#pragma unroll
          for (int p = 0; p < KNN; ++p) ins15(fin, scratch[(t * 4 + s) * KNN + p]);
        int jj = ct * 128 + nh * 64 + t;
#pragma unroll
        for (int p = 0; p < KNN; ++p) part[((size_t)(rt * KNN + p)) * BB + jj] = fin[p];
      }
    }
    __syncthreads();
  }

  // merge the 2 per-side row lists, write slot ct
  if (t < 256) {
#pragma unroll
    for (int p = 0; p < KNN; ++p) scratch[(scanrow * 2 + side) * KNN + p] = rowlist[p];
  }
  __syncthreads();
  if (t < 128) {
    unsigned fin[KNN];
#pragma unroll
    for (int p = 0; p < KNN; ++p) fin[p] = 0xFFFFFFFFu;
    for (int s = 0; s < 2; ++s)
#pragma unroll
      for (int p = 0; p < KNN; ++p) ins15(fin, scratch[(t * 2 + s) * KNN + p]);
    int i = r0 + t;
#pragma unroll
    for (int p = 0; p < KNN; ++p) part[((size_t)(ct * KNN + p)) * BB + i] = fin[p];
  }
}

// ---------------- merge stage 1: 64 slots -> 4, early-exit on sorted slots ----------------
__global__ void k_merge1(const unsigned* __restrict__ part, unsigned* __restrict__ part2) {
  int gid = blockIdx.x * 256 + threadIdx.x;  // 32768
  int s = gid >> 13, i = gid & 8191;
  unsigned l[KNN];
#pragma unroll
  for (int p = 0; p < KNN; ++p) l[p] = 0xFFFFFFFFu;
  for (int b = s * 16; b < s * 16 + 16; ++b) {
    size_t base = (size_t)(b * KNN) * BB + i;
    unsigned u = part[base];
    if (u < l[KNN - 1]) {
      ins15(l, u);
      for (int p = 1; p < KNN; ++p) {
        u = part[base + (size_t)p * BB];
        if (u >= l[KNN - 1]) break;
        ins15(l, u);
      }
    }
  }
#pragma unroll
  for (int p = 0; p < KNN; ++p) part2[((size_t)(s * KNN + p)) * BB + i] = l[p];
}

// ---------------- merge stage 2: final top-15 + xmax ----------------
__global__ void k_merge2(const unsigned* __restrict__ part2, float* __restrict__ knn_d2,
                         int* __restrict__ knn_idx, int* __restrict__ xmax_bits) {
  int i = blockIdx.x * 256 + threadIdx.x;
  unsigned l[KNN];
#pragma unroll
  for (int p = 0; p < KNN; ++p) l[p] = 0xFFFFFFFFu;
  for (int q = 0; q < 4; ++q) {
    size_t base = (size_t)(q * KNN) * BB + i;
    unsigned u = part2[base];
    if (u < l[KNN - 1]) {
      ins15(l, u);
      for (int p = 1; p < KNN; ++p) {
        u = part2[base + (size_t)p * BB];
        if (u >= l[KNN - 1]) break;
        ins15(l, u);
      }
    }
  }
  float mx = 0.f;
#pragma unroll
  for (int p = 0; p < KNN; ++p) {
    unsigned u = l[p];
    float d = fmaxf(unpack_d2(u), 0.f);
    mx = fmaxf(mx, d);
    knn_d2[(size_t)i * KNN + p] = d;
    knn_idx[(size_t)i * KNN + p] = (int)(u & 0xFFFFu);
  }
  int t = threadIdx.x;
#pragma unroll
  for (int off = 32; off >= 1; off >>= 1) mx = fmaxf(mx, __shfl_down(mx, off));
  __shared__ float rm[4];
  if ((t & 63) == 0) rm[t >> 6] = mx;
  __syncthreads();
  if (t == 0) {
    float mb = fmaxf(fmaxf(rm[0], rm[1]), fmaxf(rm[2], rm[3]));
    atomicMax(xmax_bits, __float_as_int(mb));
  }
}

// ---------------- fused edge kernel: zd2 + reciprocity + partial sums ----------------
__global__ void k_edge(const float* __restrict__ z, const int* __restrict__ knn_idx,
                       const float* __restrict__ knn_d2, float* __restrict__ pzz,
                       float* __restrict__ pxx, float* __restrict__ pxz,
                       float* __restrict__ pcnt, float* __restrict__ pzm) {
  int t = threadIdx.x;
  int g = t >> 4, L = t & 15;
  int lane = t & 63;
  float szz = 0.f, sxx = 0.f, sxz = 0.f, scnt = 0.f, zm = 0.f;
#pragma unroll
  for (int pass = 0; pass < 8; ++pass) {
    int e = blockIdx.x * 128 + pass * 16 + g;
    int i = e / KNN;
    int j = knn_idx[e];
    f32x4 zi = *(const f32x4*)(z + (size_t)i * LL + L * 4);
    f32x4 zj = *(const f32x4*)(z + (size_t)j * LL + L * 4);
    float v = 0.f;
#pragma unroll
    for (int d = 0; d < 4; ++d) {
      float df = zi[d] - zj[d];
      v = fmaf(df, df, v);
    }
    v += __shfl_down(v, 8);
    v += __shfl_down(v, 4);
    v += __shfl_down(v, 2);
    v += __shfl_down(v, 1);
    int cand = (L < KNN) ? knn_idx[(size_t)j * KNN + L] : -1;
    unsigned long long ball = __ballot(cand == i);
    unsigned recip = (unsigned)(ball >> (lane & 48)) & 0xFFFFu;
    if (L == 0) {
      float w = recip ? 1.f : 2.f;
      float xd2 = knn_d2[e];
      szz = fmaf(w, v, szz);
      sxx = fmaf(w, xd2, sxx);
      sxz = fmaf(w, sqrtf(v * xd2), sxz);
      scnt += w;
      zm = fmaxf(zm, v);
    }
  }
#pragma unroll
  for (int off = 32; off >= 1; off >>= 1) {
    szz += __shfl_down(szz, off);
    sxx += __shfl_down(sxx, off);
    sxz += __shfl_down(sxz, off);
    scnt += __shfl_down(scnt, off);
    zm = fmaxf(zm, __shfl_down(zm, off));
  }
  __shared__ float r[5][4];
  int w4 = t >> 6;
  if (lane == 0) {
    r[0][w4] = szz; r[1][w4] = sxx; r[2][w4] = sxz; r[3][w4] = scnt; r[4][w4] = zm;
  }
  __syncthreads();
  if (t == 0) {
    pzz[blockIdx.x] = r[0][0] + r[0][1] + r[0][2] + r[0][3];
    pxx[blockIdx.x] = r[1][0] + r[1][1] + r[1][2] + r[1][3];
    pxz[blockIdx.x] = r[2][0] + r[2][1] + r[2][2] + r[2][3];
    pcnt[blockIdx.x] = r[3][0] + r[3][1] + r[3][2] + r[3][3];
    pzm[blockIdx.x] = fmaxf(fmaxf(r[4][0], r[4][1]), fmaxf(r[4][2], r[4][3]));
  }
}

// ---------------- final: reduce partials, assemble scalar loss ----------------
__global__ void k_final(const float* __restrict__ pzz, const float* __restrict__ pxx,
                        const float* __restrict__ pxz, const float* __restrict__ pcnt,
                        const float* __restrict__ pzm, const int* __restrict__ xmax_bits,
                        const float* __restrict__ rec_sum, float* __restrict__ out) {
  int t = threadIdx.x;
  float szz = 0.f, sxx = 0.f, sxz = 0.f, scnt = 0.f, zm = 0.f;
  for (int bb = t; bb < NEBLK; bb += 256) {
    szz += pzz[bb];
    sxx += pxx[bb];
    sxz += pxz[bb];
    scnt += pcnt[bb];
    zm = fmaxf(zm, pzm[bb]);
  }
#pragma unroll
  for (int off = 32; off >= 1; off >>= 1) {
    szz += __shfl_down(szz, off);
    sxx += __shfl_down(sxx, off);
    sxz += __shfl_down(sxz, off);
    scnt += __shfl_down(scnt, off);
    zm = fmaxf(zm, __shfl_down(zm, off));
  }
  __shared__ float r[5][4];
  int w4 = t >> 6;
  if ((t & 63) == 0) {
    r[0][w4] = szz; r[1][w4] = sxx; r[2][w4] = sxz; r[3][w4] = scnt; r[4][w4] = zm;
  }
  __syncthreads();
  if (t == 0) {
    float SZZ = r[0][0] + r[0][1] + r[0][2] + r[0][3];
    float SXX = r[1][0] + r[1][1] + r[1][2] + r[1][3];
    float SXZ = r[2][0] + r[2][1] + r[2][2] + r[2][3];
    float CNT = r[3][0] + r[3][1] + r[3][2] + r[3][3];
    float ZM = fmaxf(fmaxf(r[4][0], r[4][1]), fmaxf(r[4][2], r[4][3]));
    float xmax = __int_as_float(*xmax_bits);
    float a = 1.f / (sqrtf(ZM) + 1e-8f);
    float bq = 1.f / (sqrtf(xmax) + 1e-8f);
    float loss = (a * a * SZZ + bq * bq * SXX - 2.f * a * bq * SXZ) / CNT;
    out[0] = rec_sum[0] * (1.f / 8388608.f) + loss;
  }
}

extern "C" void kernel_launch(void* const* d_in, const int* in_sizes, int n_in,
                              void* d_out, int out_size, void* d_ws, size_t ws_size,
                              hipStream_t stream) {
  const float* x = (const float*)d_in[0];
  const float* We1 = (const float*)d_in[1];
  const float* be1 = (const float*)d_in[2];
  const float* We2 = (const float*)d_in[3];
  const float* be2 = (const float*)d_in[4];
  const float* Wd1 = (const float*)d_in[5];
  const float* bd1 = (const float*)d_in[6];
  const float* Wd2 = (const float*)d_in[7];
  const float* bd2 = (const float*)d_in[8];

  char* ws = (char*)d_ws;
  size_t off = 0;
  auto alloc = [&](size_t bytes) {
    void* p = ws + off;
    off += (bytes + 255) & ~(size_t)255;
    return p;
  };
  unsigned short* xb = (unsigned short*)alloc((size_t)BB * DD * 2);
  unsigned short* hb = (unsigned short*)alloc((size_t)BB * HH * 2);
  unsigned short* zb = (unsigned short*)alloc((size_t)BB * LL * 2);
  unsigned short* h2b = (unsigned short*)alloc((size_t)BB * HH * 2);
  float* z = (float*)alloc((size_t)BB * LL * 4);
  float* sqx = (float*)alloc((size_t)BB * 4);
  unsigned short* Wt1 = (unsigned short*)alloc((size_t)HH * DD * 2);
  unsigned short* Wt2 = (unsigned short*)alloc((size_t)LL * HH * 2);
  unsigned short* Wt3 = (unsigned short*)alloc((size_t)HH * LL * 2);
  unsigned short* Wt4 = (unsigned short*)alloc((size_t)DD * HH * 2);
  unsigned* part = (unsigned*)alloc((size_t)NT * KNN * BB * 4);   // 31.5MB
  unsigned* part2 = (unsigned*)alloc((size_t)4 * KNN * BB * 4);   // 2MB
  float* knn_d2 = (float*)alloc((size_t)BB * KNN * 4);
  int* knn_idx = (int*)alloc((size_t)BB * KNN * 4);
  float* pzz = (float*)alloc(NEBLK * 4);
  float* pxx = (float*)alloc(NEBLK * 4);
  float* pxz = (float*)alloc(NEBLK * 4);
  float* pcnt = (float*)alloc(NEBLK * 4);
  float* pzm = (float*)alloc(NEBLK * 4);
  float* scal = (float*)alloc(64);
  float* rec_sum = scal + 0;
  int* xmax_bits = (int*)(scal + 1);

  hipMemsetAsync(scal, 0, 64, stream);

  k_prep<<<BB + 272, 256, 0, stream>>>(x, xb, sqx, We1, We2, Wd1, Wd2, Wt1, Wt2, Wt3, Wt4);

  // fat kernel: G1 (256 blocks) + gram/top-15 (2080 blocks), 512 threads
  k_gram_topk<<<NG1 + NTILES, 512, 0, stream>>>(xb, sqx, part, Wt1, be1, hb);

  k_mgemm<2, 0, 0, 1, 1><<<dim3(LL / 64, BB / 128), 256, 0, stream>>>(
      hb, Wt2, be2, zb, z, nullptr, nullptr, LL, HH);
  k_mgemm<4, 1, 0, 0, 1><<<dim3(HH / 128, BB / 128), 256, 0, stream>>>(
      zb, Wt3, bd1, h2b, nullptr, nullptr, nullptr, HH, LL);
  k_mgemm<4, 0, 1, 0, 0><<<dim3(DD / 128, BB / 128), 256, 0, stream>>>(
      h2b, Wt4, bd2, nullptr, nullptr, x, rec_sum, DD, HH);

  k_merge1<<<128, 256, 0, stream>>>(part, part2);
  k_merge2<<<BB / 256, 256, 0, stream>>>(part2, knn_d2, knn_idx, xmax_bits);
  k_edge<<<NEBLK, 256, 0, stream>>>(z, knn_idx, knn_d2, pzz, pxx, pxz, pcnt, pzm);
  k_final<<<1, 256, 0, stream>>>(pzz, pxx, pxz, pcnt, pzm, xmax_bits, rec_sum, (float*)d_out);
}

// Round 15
// 324.975 us; speedup vs baseline: 1.4096x; 1.0760x over previous
//
#include <hip/hip_runtime.h>

#define BB 8192
#define DD 1024
#define HH 512
#define LL 64
#define KNN 15
#define NT 64            // 8192/128 tiles per dim
#define NTILES 2080      // NT*(NT+1)/2
#define NG1 256          // fused G1 blocks
#define NEDGE (BB * KNN)
#define NEBLK (NEDGE / 128)  // 960 edge blocks

typedef __attribute__((ext_vector_type(4))) float f32x4;
typedef __attribute__((ext_vector_type(8))) short s16x8;
typedef __attribute__((ext_vector_type(8))) unsigned short u16x8;
typedef __attribute__((ext_vector_type(4))) unsigned short u16x4;
typedef __attribute__((ext_vector_type(4))) _Float16 f16x4;

typedef s16x8 fragT;

__device__ __forceinline__ unsigned short f2bf(float f) {
  unsigned u = __float_as_uint(f);
  return (unsigned short)((u + 0x7fffu + ((u >> 16) & 1u)) >> 16);  // RNE
}

__device__ __forceinline__ void gload16(const void* g, void* l) {
  __builtin_amdgcn_global_load_lds((const __attribute__((address_space(1))) unsigned int*)g,
                                   (__attribute__((address_space(3))) unsigned int*)l, 16, 0, 0);
}

__device__ __forceinline__ float unpack_d2(unsigned u) {
  _Float16 h = __builtin_bit_cast(_Float16, (unsigned short)(u >> 16));
  return (float)h;
}

// sorted ascending top-15 insert via min/max network
__device__ __forceinline__ void ins15(unsigned (&l)[KNN], unsigned u) {
  if (u < l[KNN - 1]) {
    unsigned v = u;
#pragma unroll
    for (int p = 0; p < KNN; ++p) {
      unsigned lo = min(v, l[p]);
      unsigned hi = max(v, l[p]);
      l[p] = lo;
      v = hi;
    }
  }
}

// ---------------- prep: x->bf16+norms (blocks 0..8191) + 4 weight transposes ----------------
__global__ void k_prep(const float* __restrict__ x, unsigned short* __restrict__ xb,
                       float* __restrict__ sqx,
                       const float* __restrict__ We1, const float* __restrict__ We2,
                       const float* __restrict__ Wd1, const float* __restrict__ Wd2,
                       unsigned short* __restrict__ Wt1, unsigned short* __restrict__ Wt2,
                       unsigned short* __restrict__ Wt3, unsigned short* __restrict__ Wt4) {
  __shared__ float ps[4];
  __shared__ unsigned short T[64][65];
  int b = blockIdx.x;
  int t = threadIdx.x;
  if (b < BB) {
    f32x4 v = *(const f32x4*)(x + (size_t)b * DD + t * 4);
    u16x4 o;
    float s = 0.f;
#pragma unroll
    for (int j = 0; j < 4; ++j) {
      float f = v[j];
      s += f * f;
      o[j] = f2bf(f);
    }
    *(u16x4*)(xb + (size_t)b * DD + t * 4) = o;
#pragma unroll
    for (int off = 32; off >= 1; off >>= 1) s += __shfl_down(s, off);
    if ((t & 63) == 0) ps[t >> 6] = s;
    __syncthreads();
    if (t == 0) sqx[b] = ps[0] + ps[1] + ps[2] + ps[3];
    return;
  }
  int c = b - BB;
  const float* W;
  unsigned short* Wt;
  int Kd, N, idx;
  if (c < 128)      { W = We1; Wt = Wt1; Kd = DD; N = HH; idx = c; }
  else if (c < 136) { W = We2; Wt = Wt2; Kd = HH; N = LL; idx = c - 128; }
  else if (c < 144) { W = Wd1; Wt = Wt3; Kd = LL; N = HH; idx = c - 136; }
  else              { W = Wd2; Wt = Wt4; Kd = HH; N = DD; idx = c - 144; }
  int nx = Kd >> 6;
  int k0 = (idx % nx) * 64, n0 = (idx / nx) * 64;
  int kr = t >> 4, nc = (t & 15) * 4;
#pragma unroll
  for (int q = 0; q < 4; ++q) {
    int k = kr + q * 16;
    f32x4 v = *(const f32x4*)(W + (size_t)(k0 + k) * N + n0 + nc);
#pragma unroll
    for (int j = 0; j < 4; ++j) T[nc + j][k] = f2bf(v[j]);
  }
  __syncthreads();
#pragma unroll
  for (int q = 0; q < 2; ++q) {
    int s = t + q * 256;
    int n = s >> 3, cc = (s & 7) * 8;
    u16x8 o;
#pragma unroll
    for (int j = 0; j < 8; ++j) o[j] = T[n][cc + j];
    *(u16x8*)(Wt + (size_t)(n0 + n) * Kd + k0 + cc) = o;
  }
}

// ---------------- MFMA-GEMM body (256 thr, 2-phase) for G1..G4 ----------------
template <int NF, int RELU, int FUSE, int STF32, int STBF>
__device__ __forceinline__ void mgemm_body(
    char* LB, int m0, int n0,
    const unsigned short* __restrict__ A, const unsigned short* __restrict__ Wt,
    const float* __restrict__ bias, unsigned short* __restrict__ Cb, float* __restrict__ Cf,
    const float* __restrict__ Xref, float* __restrict__ rec_sum, int N, int Kd) {
  unsigned short* At = (unsigned short*)LB;
  unsigned short* Bt = (unsigned short*)(LB + 16384);
  int t = threadIdx.x;
  int lane = t & 63, w = t >> 6;
  int wr = w >> 1, wc = w & 1;
  int wbase = w * 64;

  const unsigned short* pA[4];
  const unsigned short* pB[NF];
#pragma unroll
  for (int q = 0; q < 4; ++q) {
    int s = q * 256 + t;
    int r = s >> 3, g = s & 7;
    pA[q] = A + (size_t)(m0 + r) * Kd + (g ^ (r & 7)) * 8;
  }
#pragma unroll
  for (int q = 0; q < NF; ++q) {
    int s = q * 256 + t;
    int r = s >> 3, g = s & 7;
    pB[q] = Wt + (size_t)(n0 + r) * Kd + (g ^ (r & 7)) * 8;
  }

  int lrow = lane & 15;
  int klo = (lane >> 4) << 4;
  int sw = (lane & 7) << 4;

  f32x4 acc[4][NF] = {};

  int ksteps = Kd >> 6;
#pragma unroll
  for (int q = 0; q < 4; ++q) { gload16(pA[q], At + (q * 256 + wbase) * 8); pA[q] += 64; }
#pragma unroll
  for (int q = 0; q < NF; ++q) { gload16(pB[q], Bt + (q * 256 + wbase) * 8); pB[q] += 64; }

  for (int kt = 0; kt < ksteps; ++kt) {
    __syncthreads();
    fragT af[2][4], bf[2][NF];
#pragma unroll
    for (int kh = 0; kh < 2; ++kh) {
      int kbyte = ((kh << 6) | klo) ^ sw;
#pragma unroll
      for (int m = 0; m < 4; ++m)
        af[kh][m] = *(const fragT*)((const char*)At + (wr * 64 + m * 16 + lrow) * 128 + kbyte);
#pragma unroll
      for (int n = 0; n < NF; ++n)
        bf[kh][n] = *(const fragT*)((const char*)Bt + (wc * NF * 16 + n * 16 + lrow) * 128 + kbyte);
    }
    __syncthreads();
    if (kt + 1 < ksteps) {
#pragma unroll
      for (int q = 0; q < 4; ++q) { gload16(pA[q], At + (q * 256 + wbase) * 8); pA[q] += 64; }
#pragma unroll
      for (int q = 0; q < NF; ++q) { gload16(pB[q], Bt + (q * 256 + wbase) * 8); pB[q] += 64; }
    }
#pragma unroll
    for (int kh = 0; kh < 2; ++kh)
#pragma unroll
      for (int m = 0; m < 4; ++m)
#pragma unroll
        for (int n = 0; n < NF; ++n)
          acc[m][n] =
              __builtin_amdgcn_mfma_f32_16x16x32_bf16(af[kh][m], bf[kh][n], acc[m][n], 0, 0, 0);
  }

  float local = 0.f;
#pragma unroll
  for (int m = 0; m < 4; ++m) {
    int row0 = m0 + wr * 64 + m * 16 + ((lane >> 4) << 2);
#pragma unroll
    for (int n = 0; n < NF; ++n) {
      int col = n0 + wc * NF * 16 + n * 16 + lrow;
      float bv = bias[col];
      f32x4 a = acc[m][n];
#pragma unroll
      for (int j = 0; j < 4; ++j) {
        float c = a[j] + bv;
        if (RELU) c = fmaxf(c, 0.f);
        if (FUSE) {
          float xv = Xref[(size_t)(row0 + j) * N + col];
          float d = c - xv;
          local = fmaf(d, d, local);
        }
        if (STBF) Cb[(size_t)(row0 + j) * N + col] = f2bf(c);
        if (STF32) Cf[(size_t)(row0 + j) * N + col] = c;
      }
    }
  }
  if (FUSE) {
#pragma unroll
    for (int off = 32; off >= 1; off >>= 1) local += __shfl_down(local, off);
    __shared__ float rs[4];
    if ((t & 63) == 0) rs[t >> 6] = local;
    __syncthreads();
    if (t == 0) atomicAdd(rec_sum, rs[0] + rs[1] + rs[2] + rs[3]);
  }
}

template <int NF, int RELU, int FUSE, int STF32, int STBF>
__global__ __launch_bounds__(256) void k_mgemm(
    const unsigned short* __restrict__ A, const unsigned short* __restrict__ Wt,
    const float* __restrict__ bias, unsigned short* __restrict__ Cb, float* __restrict__ Cf,
    const float* __restrict__ Xref, float* __restrict__ rec_sum, int N, int Kd) {
  __shared__ __attribute__((aligned(16))) char LB[16384 + NF * 32 * 128];
  mgemm_body<NF, RELU, FUSE, STF32, STBF>(LB, blockIdx.y * 128, blockIdx.x * (NF * 32),
                                          A, Wt, bias, Cb, Cf, Xref, rec_sum, N, Kd);
}

// ---------------- fat kernel: G1 (256 blocks) + Gram/top-15 ----------------
// Gram K-loop: BK=32 DOUBLE-buffered, raw s_barrier + counted vmcnt(4) so the next
// stage's global_load_lds stay in flight across barriers (T4). LDS layout:
// [A0 8K][A1 8K][B0 8K][B1 8K] = 32KB; Sf(16K) overlays A0+A1, scratch overlays B0+B1.
__global__ __launch_bounds__(256, 3) void k_gram_topk(
    const unsigned short* __restrict__ xb, const float* __restrict__ sqx,
    unsigned* __restrict__ part,
    const unsigned short* __restrict__ Wt1, const float* __restrict__ be1,
    unsigned short* __restrict__ hb) {
  __shared__ __attribute__((aligned(16))) char LB[33792];

  int bid0 = blockIdx.x;
  if (bid0 < NG1) {
    mgemm_body<4, 1, 0, 0, 1>(LB, (bid0 >> 2) * 128, (bid0 & 3) * 128,
                              xb, Wt1, be1, hb, nullptr, nullptr, nullptr, HH, DD);
    return;
  }

  char* Sf = LB;                                  // scan phase (overlays A0+A1)
  unsigned* scratch = (unsigned*)(LB + 16384);    // scan phase (overlays B0+B1)
  float* sqr = (float*)(LB + 32768);
  float* sqc = (float*)(LB + 33280);

  int g = bid0 - NG1;
  int k = g & 7, m = g >> 3;
  int nA = 6 + 4 * (61 - 4 * k);
  int b, mm;
  if (m < nA) { b = k; mm = m; }
  else        { b = 15 - k; mm = m - nA; }
  int ctl, j;
  if (mm < 6) {
    if (mm < 1)      { ctl = 0; j = mm; }
    else if (mm < 3) { ctl = 1; j = mm - 1; }
    else             { ctl = 2; j = mm - 3; }
  } else {
    ctl = 3 + ((mm - 6) >> 2);
    j = (mm - 6) & 3;
  }
  int rt = 4 * b + j;
  int ct = 4 * b + ctl;
  bool diag = (rt == ct);
  int r0 = rt * 128, c0 = ct * 128;

  int t = threadIdx.x;
  int lane = t & 63, w = t >> 6;
  int wr = w >> 1, wc = w & 1;

  if (t < 128) {
    sqr[t] = sqx[r0 + t];
    sqc[t] = sqx[c0 + t];
  }

  // staging: BK=32 -> 512 slots x 16B per (matrix,buffer); thread t -> slots {t, t+256}
  const unsigned short* pA[2];
  const unsigned short* pB[2];
  int dsto[2];
#pragma unroll
  for (int q = 0; q < 2; ++q) {
    int s = q * 256 + t;
    int r = s >> 2, g2 = s & 3;
    int ksh = (g2 ^ (r & 3)) * 8;  // shorts within 32-short window
    pA[q] = xb + (size_t)(r0 + r) * DD + ksh;
    pB[q] = xb + (size_t)(c0 + r) * DD + ksh;
    dsto[q] = s * 8;  // shorts
  }

  int lrow = lane & 15;
  int chx = ((lane >> 4) ^ (lane & 3)) << 4;  // swizzled 16B chunk (row&3 == lane&3)

  f32x4 acc[16] = {};

  auto STAGE = [&](int buf) {
    unsigned short* dA = (unsigned short*)LB + buf * 4096;
    unsigned short* dB = (unsigned short*)(LB + 16384) + buf * 4096;
#pragma unroll
    for (int q = 0; q < 2; ++q) {
      gload16(pA[q], dA + dsto[q]); pA[q] += 32;
      gload16(pB[q], dB + dsto[q]); pB[q] += 32;
    }
  };

  STAGE(0);
  STAGE(1);

  for (int kt = 0; kt < 32; ++kt) {
    if (kt < 31) {
      asm volatile("s_waitcnt vmcnt(4)" ::: "memory");  // own stage(kt) landed, kt+1 in flight
    } else {
      asm volatile("s_waitcnt vmcnt(0)" ::: "memory");
    }
    __builtin_amdgcn_s_barrier();                        // all waves' stage(kt) landed
    __builtin_amdgcn_sched_barrier(0);
    const char* Ab = (const char*)LB + (kt & 1) * 8192;
    const char* Bb = (const char*)LB + 16384 + (kt & 1) * 8192;
    fragT af[4], bf[4];
#pragma unroll
    for (int mq = 0; mq < 4; ++mq)
      af[mq] = *(const fragT*)(Ab + (wr * 64 + mq * 16 + lrow) * 64 + chx);
#pragma unroll
    for (int n = 0; n < 4; ++n)
      bf[n] = *(const fragT*)(Bb + (wc * 64 + n * 16 + lrow) * 64 + chx);
    asm volatile("s_waitcnt lgkmcnt(0)" ::: "memory");   // frags in regs
    __builtin_amdgcn_sched_barrier(0);
    __builtin_amdgcn_s_barrier();                        // all waves done reading buf(kt&1)
    if (kt + 2 < 32) STAGE(kt & 1);                      // overwrite freed buffer
#pragma unroll
    for (int mq = 0; mq < 4; ++mq)
#pragma unroll
      for (int n = 0; n < 4; ++n)
        acc[mq * 4 + n] =
            __builtin_amdgcn_mfma_f32_16x16x32_bf16(af[mq], bf[n], acc[mq * 4 + n], 0, 0, 0);
  }

  unsigned rowlist[KNN];
#pragma unroll
  for (int p = 0; p < KNN; ++p) rowlist[p] = 0xFFFFFFFFu;

  int scanrow = t & 127, side = t >> 7;

#pragma unroll
  for (int nh = 0; nh < 2; ++nh) {
    // write d2 half-tile (cols nh*64..+63) to swizzled f16 Sf
    if (wc == nh) {
#pragma unroll
      for (int mq = 0; mq < 4; ++mq) {
        int row0 = wr * 64 + mq * 16 + ((lane >> 4) << 2);
        f32x4 sq4 = *(const f32x4*)&sqr[row0];
#pragma unroll
        for (int n = 0; n < 4; ++n) {
          int colL = n * 16 + lrow;
          float sc = sqc[nh * 64 + colL];
          f32x4 a = acc[mq * 4 + n];
          f16x4 hv;
#pragma unroll
          for (int r = 0; r < 4; ++r) {
            float d2 = fmaxf(sq4[r] + sc - 2.f * a[r], 0.f);
            if (diag && (row0 + r == nh * 64 + colL)) d2 = 60000.f;
            hv[r] = (_Float16)d2;
          }
          *(f16x4*)(Sf + colL * 256 + ((row0 * 2) ^ ((colL & 31) << 3))) = hv;
        }
      }
    }
    __syncthreads();
    // row-scan: 2 threads/row, 32 cols each; chunk-of-4 min prefilter
    {
      int cbase = side * 32;
      int jbase = c0 + nh * 64;
      for (int cc = 0; cc < 32; cc += 4) {
        unsigned u[4];
#pragma unroll
        for (int q = 0; q < 4; ++q) {
          int colL = cbase + cc + q;
          unsigned bits = *(const unsigned short*)(Sf + colL * 256 +
                                                   ((scanrow * 2) ^ ((colL & 31) << 3)));
          u[q] = (bits << 16) | (unsigned)(jbase + colL);
        }
        unsigned m4 = min(min(u[0], u[1]), min(u[2], u[3]));
        if (m4 < rowlist[KNN - 1]) {
#pragma unroll
          for (int q = 0; q < 4; ++q) ins15(rowlist, u[q]);
        }
      }
    }
    // col-scan: b64 loads of 4 consecutive rows + min prefilter
    if (!diag) {
      int c = t & 63, seg = t >> 6;
      unsigned collist[KNN];
#pragma unroll
      for (int p = 0; p < KNN; ++p) collist[p] = 0xFFFFFFFFu;
      for (int rq = 0; rq < 8; ++rq) {
        int r = seg * 32 + rq * 4;
        u16x4 v4 = *(const u16x4*)(Sf + c * 256 + ((r * 2) ^ ((c & 31) << 3)));
        unsigned u[4];
#pragma unroll
        for (int jj = 0; jj < 4; ++jj) u[jj] = ((unsigned)v4[jj] << 16) | (unsigned)(r0 + r + jj);
        unsigned m4 = min(min(u[0], u[1]), min(u[2], u[3]));
        if (m4 < collist[KNN - 1]) {
#pragma unroll
          for (int jj = 0; jj < 4; ++jj) ins15(collist, u[jj]);
        }
      }
      __syncthreads();
#pragma unroll
      for (int p = 0; p < KNN; ++p) scratch[(c * 4 + seg) * KNN + p] = collist[p];
      __syncthreads();
      if (t < 64) {
        unsigned fin[KNN];
#pragma unroll
        for (int p = 0; p < KNN; ++p) fin[p] = 0xFFFFFFFFu;
        for (int s = 0; s < 4; ++s)
#pragma unroll
          for (int p = 0; p < KNN; ++p) ins15(fin, scratch[(t * 4 + s) * KNN + p]);
        int jj = c0 + nh * 64 + t;
#pragma unroll
        for (int p = 0; p < KNN; ++p) part[((size_t)(rt * KNN + p)) * BB + jj] = fin[p];
      }
    }
    __syncthreads();
  }

  // merge the 2 per-side row lists, write slot ct
#pragma unroll
  for (int p = 0; p < KNN; ++p) scratch[(scanrow * 2 + side) * KNN + p] = rowlist[p];
  __syncthreads();
  if (t < 128) {
    unsigned fin[KNN];
#pragma unroll
    for (int p = 0; p < KNN; ++p) fin[p] = 0xFFFFFFFFu;
    for (int s = 0; s < 2; ++s)
#pragma unroll
      for (int p = 0; p < KNN; ++p) ins15(fin, scratch[(t * 2 + s) * KNN + p]);
    int i = r0 + t;
#pragma unroll
    for (int p = 0; p < KNN; ++p) part[((size_t)(ct * KNN + p)) * BB + i] = fin[p];
  }
}

// ---------------- merge stage 1: 64 slots -> 4, early-exit on sorted slots ----------------
__global__ void k_merge1(const unsigned* __restrict__ part, unsigned* __restrict__ part2) {
  int gid = blockIdx.x * 256 + threadIdx.x;  // 32768
  int s = gid >> 13, i = gid & 8191;
  unsigned l[KNN];
#pragma unroll
  for (int p = 0; p < KNN; ++p) l[p] = 0xFFFFFFFFu;
  for (int b = s * 16; b < s * 16 + 16; ++b) {
    size_t base = (size_t)(b * KNN) * BB + i;
    unsigned u = part[base];
    if (u < l[KNN - 1]) {
      ins15(l, u);
      for (int p = 1; p < KNN; ++p) {
        u = part[base + (size_t)p * BB];
        if (u >= l[KNN - 1]) break;
        ins15(l, u);
      }
    }
  }
#pragma unroll
  for (int p = 0; p < KNN; ++p) part2[((size_t)(s * KNN + p)) * BB + i] = l[p];
}

// ---------------- merge stage 2: final top-15 + xmax ----------------
__global__ void k_merge2(const unsigned* __restrict__ part2, float* __restrict__ knn_d2,
                         int* __restrict__ knn_idx, int* __restrict__ xmax_bits) {
  int i = blockIdx.x * 256 + threadIdx.x;
  unsigned l[KNN];
#pragma unroll
  for (int p = 0; p < KNN; ++p) l[p] = 0xFFFFFFFFu;
  for (int q = 0; q < 4; ++q) {
    size_t base = (size_t)(q * KNN) * BB + i;
    unsigned u = part2[base];
    if (u < l[KNN - 1]) {
      ins15(l, u);
      for (int p = 1; p < KNN; ++p) {
        u = part2[base + (size_t)p * BB];
        if (u >= l[KNN - 1]) break;
        ins15(l, u);
      }
    }
  }
  float mx = 0.f;
#pragma unroll
  for (int p = 0; p < KNN; ++p) {
    unsigned u = l[p];
    float d = fmaxf(unpack_d2(u), 0.f);
    mx = fmaxf(mx, d);
    knn_d2[(size_t)i * KNN + p] = d;
    knn_idx[(size_t)i * KNN + p] = (int)(u & 0xFFFFu);
  }
  int t = threadIdx.x;
#pragma unroll
  for (int off = 32; off >= 1; off >>= 1) mx = fmaxf(mx, __shfl_down(mx, off));
  __shared__ float rm[4];
  if ((t & 63) == 0) rm[t >> 6] = mx;
  __syncthreads();
  if (t == 0) {
    float mb = fmaxf(fmaxf(rm[0], rm[1]), fmaxf(rm[2], rm[3]));
    atomicMax(xmax_bits, __float_as_int(mb));
  }
}

// ---------------- fused edge kernel: zd2 + reciprocity + partial sums ----------------
__global__ void k_edge(const float* __restrict__ z, const int* __restrict__ knn_idx,
                       const float* __restrict__ knn_d2, float* __restrict__ pzz,
                       float* __restrict__ pxx, float* __restrict__ pxz,
                       float* __restrict__ pcnt, float* __restrict__ pzm) {
  int t = threadIdx.x;
  int g = t >> 4, L = t & 15;
  int lane = t & 63;
  float szz = 0.f, sxx = 0.f, sxz = 0.f, scnt = 0.f, zm = 0.f;
#pragma unroll
  for (int pass = 0; pass < 8; ++pass) {
    int e = blockIdx.x * 128 + pass * 16 + g;
    int i = e / KNN;
    int j = knn_idx[e];
    f32x4 zi = *(const f32x4*)(z + (size_t)i * LL + L * 4);
    f32x4 zj = *(const f32x4*)(z + (size_t)j * LL + L * 4);
    float v = 0.f;
#pragma unroll
    for (int d = 0; d < 4; ++d) {
      float df = zi[d] - zj[d];
      v = fmaf(df, df, v);
    }
    v += __shfl_down(v, 8);
    v += __shfl_down(v, 4);
    v += __shfl_down(v, 2);
    v += __shfl_down(v, 1);
    int cand = (L < KNN) ? knn_idx[(size_t)j * KNN + L] : -1;
    unsigned long long ball = __ballot(cand == i);
    unsigned recip = (unsigned)(ball >> (lane & 48)) & 0xFFFFu;
    if (L == 0) {
      float w = recip ? 1.f : 2.f;
      float xd2 = knn_d2[e];
      szz = fmaf(w, v, szz);
      sxx = fmaf(w, xd2, sxx);
      sxz = fmaf(w, sqrtf(v * xd2), sxz);
      scnt += w;
      zm = fmaxf(zm, v);
    }
  }
#pragma unroll
  for (int off = 32; off >= 1; off >>= 1) {
    szz += __shfl_down(szz, off);
    sxx += __shfl_down(sxx, off);
    sxz += __shfl_down(sxz, off);
    scnt += __shfl_down(scnt, off);
    zm = fmaxf(zm, __shfl_down(zm, off));
  }
  __shared__ float r[5][4];
  int w4 = t >> 6;
  if (lane == 0) {
    r[0][w4] = szz; r[1][w4] = sxx; r[2][w4] = sxz; r[3][w4] = scnt; r[4][w4] = zm;
  }
  __syncthreads();
  if (t == 0) {
    pzz[blockIdx.x] = r[0][0] + r[0][1] + r[0][2] + r[0][3];
    pxx[blockIdx.x] = r[1][0] + r[1][1] + r[1][2] + r[1][3];
    pxz[blockIdx.x] = r[2][0] + r[2][1] + r[2][2] + r[2][3];
    pcnt[blockIdx.x] = r[3][0] + r[3][1] + r[3][2] + r[3][3];
    pzm[blockIdx.x] = fmaxf(fmaxf(r[4][0], r[4][1]), fmaxf(r[4][2], r[4][3]));
  }
}

// ---------------- final: reduce partials, assemble scalar loss ----------------
__global__ void k_final(const float* __restrict__ pzz, const float* __restrict__ pxx,
                        const float* __restrict__ pxz, const float* __restrict__ pcnt,
                        const float* __restrict__ pzm, const int* __restrict__ xmax_bits,
                        const float* __restrict__ rec_sum, float* __restrict__ out) {
  int t = threadIdx.x;
  float szz = 0.f, sxx = 0.f, sxz = 0.f, scnt = 0.f, zm = 0.f;
  for (int bb = t; bb < NEBLK; bb += 256) {
    szz += pzz[bb];
    sxx += pxx[bb];
    sxz += pxz[bb];
    scnt += pcnt[bb];
    zm = fmaxf(zm, pzm[bb]);
  }
#pragma unroll
  for (int off = 32; off >= 1; off >>= 1) {
    szz += __shfl_down(szz, off);
    sxx += __shfl_down(sxx, off);
    sxz += __shfl_down(sxz, off);
    scnt += __shfl_down(scnt, off);
    zm = fmaxf(zm, __shfl_down(zm, off));
  }
  __shared__ float r[5][4];
  int w4 = t >> 6;
  if ((t & 63) == 0) {
    r[0][w4] = szz; r[1][w4] = sxx; r[2][w4] = sxz; r[3][w4] = scnt; r[4][w4] = zm;
  }
  __syncthreads();
  if (t == 0) {
    float SZZ = r[0][0] + r[0][1] + r[0][2] + r[0][3];
    float SXX = r[1][0] + r[1][1] + r[1][2] + r[1][3];
    float SXZ = r[2][0] + r[2][1] + r[2][2] + r[2][3];
    float CNT = r[3][0] + r[3][1] + r[3][2] + r[3][3];
    float ZM = fmaxf(fmaxf(r[4][0], r[4][1]), fmaxf(r[4][2], r[4][3]));
    float xmax = __int_as_float(*xmax_bits);
    float a = 1.f / (sqrtf(ZM) + 1e-8f);
    float bq = 1.f / (sqrtf(xmax) + 1e-8f);
    float loss = (a * a * SZZ + bq * bq * SXX - 2.f * a * bq * SXZ) / CNT;
    out[0] = rec_sum[0] * (1.f / 8388608.f) + loss;
  }
}

extern "C" void kernel_launch(void* const* d_in, const int* in_sizes, int n_in,
                              void* d_out, int out_size, void* d_ws, size_t ws_size,
                              hipStream_t stream) {
  const float* x = (const float*)d_in[0];
  const float* We1 = (const float*)d_in[1];
  const float* be1 = (const float*)d_in[2];
  const float* We2 = (const float*)d_in[3];
  const float* be2 = (const float*)d_in[4];
  const float* Wd1 = (const float*)d_in[5];
  const float* bd1 = (const float*)d_in[6];
  const float* Wd2 = (const float*)d_in[7];
  const float* bd2 = (const float*)d_in[8];

  char* ws = (char*)d_ws;
  size_t off = 0;
  auto alloc = [&](size_t bytes) {
    void* p = ws + off;
    off += (bytes + 255) & ~(size_t)255;
    return p;
  };
  unsigned short* xb = (unsigned short*)alloc((size_t)BB * DD * 2);
  unsigned short* hb = (unsigned short*)alloc((size_t)BB * HH * 2);
  unsigned short* zb = (unsigned short*)alloc((size_t)BB * LL * 2);
  unsigned short* h2b = (unsigned short*)alloc((size_t)BB * HH * 2);
  float* z = (float*)alloc((size_t)BB * LL * 4);
  float* sqx = (float*)alloc((size_t)BB * 4);
  unsigned short* Wt1 = (unsigned short*)alloc((size_t)HH * DD * 2);
  unsigned short* Wt2 = (unsigned short*)alloc((size_t)LL * HH * 2);
  unsigned short* Wt3 = (unsigned short*)alloc((size_t)HH * LL * 2);
  unsigned short* Wt4 = (unsigned short*)alloc((size_t)DD * HH * 2);
  unsigned* part = (unsigned*)alloc((size_t)NT * KNN * BB * 4);   // 31.5MB
  unsigned* part2 = (unsigned*)alloc((size_t)4 * KNN * BB * 4);   // 2MB
  float* knn_d2 = (float*)alloc((size_t)BB * KNN * 4);
  int* knn_idx = (int*)alloc((size_t)BB * KNN * 4);
  float* pzz = (float*)alloc(NEBLK * 4);
  float* pxx = (float*)alloc(NEBLK * 4);
  float* pxz = (float*)alloc(NEBLK * 4);
  float* pcnt = (float*)alloc(NEBLK * 4);
  float* pzm = (float*)alloc(NEBLK * 4);
  float* scal = (float*)alloc(64);
  float* rec_sum = scal + 0;
  int* xmax_bits = (int*)(scal + 1);

  hipMemsetAsync(scal, 0, 64, stream);

  k_prep<<<BB + 272, 256, 0, stream>>>(x, xb, sqx, We1, We2, Wd1, Wd2, Wt1, Wt2, Wt3, Wt4);

  // fat kernel: G1 (256 blocks) + gram/top-15 (2080 blocks)
  k_gram_topk<<<NG1 + NTILES, 256, 0, stream>>>(xb, sqx, part, Wt1, be1, hb);

  k_mgemm<2, 0, 0, 1, 1><<<dim3(LL / 64, BB / 128), 256, 0, stream>>>(
      hb, Wt2, be2, zb, z, nullptr, nullptr, LL, HH);
  k_mgemm<4, 1, 0, 0, 1><<<dim3(HH / 128, BB / 128), 256, 0, stream>>>(
      zb, Wt3, bd1, h2b, nullptr, nullptr, nullptr, HH, LL);
  k_mgemm<4, 0, 1, 0, 0><<<dim3(DD / 128, BB / 128), 256, 0, stream>>>(
      h2b, Wt4, bd2, nullptr, nullptr, x, rec_sum, DD, HH);

  k_merge1<<<128, 256, 0, stream>>>(part, part2);
  k_merge2<<<BB / 256, 256, 0, stream>>>(part2, knn_d2, knn_idx, xmax_bits);
  k_edge<<<NEBLK, 256, 0, stream>>>(z, knn_idx, knn_d2, pzz, pxx, pxz, pcnt, pzm);
  k_final<<<1, 256, 0, stream>>>(pzz, pxx, pxz, pcnt, pzm, xmax_bits, rec_sum, (float*)d_out);
}

// Round 16
// 321.518 us; speedup vs baseline: 1.4247x; 1.0108x over previous
//
#include <hip/hip_runtime.h>

#define BB 8192
#define DD 1024
#define HH 512
#define LL 64
#define KNN 15
#define NT 64            // 8192/128 tiles per dim
#define NTILES 2080      // NT*(NT+1)/2
#define NG1 256          // fused G1 blocks
#define NEDGE (BB * KNN)
#define NEBLK (NEDGE / 128)  // 960 edge blocks

typedef __attribute__((ext_vector_type(4))) float f32x4;
typedef __attribute__((ext_vector_type(8))) short s16x8;
typedef __attribute__((ext_vector_type(8))) unsigned short u16x8;
typedef __attribute__((ext_vector_type(4))) unsigned short u16x4;
typedef __attribute__((ext_vector_type(4))) _Float16 f16x4;

typedef s16x8 fragT;

__device__ __forceinline__ unsigned short f2bf(float f) {
  unsigned u = __float_as_uint(f);
  return (unsigned short)((u + 0x7fffu + ((u >> 16) & 1u)) >> 16);  // RNE
}

__device__ __forceinline__ void gload16(const void* g, void* l) {
  __builtin_amdgcn_global_load_lds((const __attribute__((address_space(1))) unsigned int*)g,
                                   (__attribute__((address_space(3))) unsigned int*)l, 16, 0, 0);
}

__device__ __forceinline__ float unpack_d2(unsigned u) {
  _Float16 h = __builtin_bit_cast(_Float16, (unsigned short)(u >> 16));
  return (float)h;
}

// sorted ascending top-15 insert via min/max network
__device__ __forceinline__ void ins15(unsigned (&l)[KNN], unsigned u) {
  if (u < l[KNN - 1]) {
    unsigned v = u;
#pragma unroll
    for (int p = 0; p < KNN; ++p) {
      unsigned lo = min(v, l[p]);
      unsigned hi = max(v, l[p]);
      l[p] = lo;
      v = hi;
    }
  }
}

// ---------------- prep: x->bf16+norms (blocks 0..8191) + 4 weight transposes ----------------
__global__ void k_prep(const float* __restrict__ x, unsigned short* __restrict__ xb,
                       float* __restrict__ sqx,
                       const float* __restrict__ We1, const float* __restrict__ We2,
                       const float* __restrict__ Wd1, const float* __restrict__ Wd2,
                       unsigned short* __restrict__ Wt1, unsigned short* __restrict__ Wt2,
                       unsigned short* __restrict__ Wt3, unsigned short* __restrict__ Wt4) {
  __shared__ float ps[4];
  __shared__ unsigned short T[64][65];
  int b = blockIdx.x;
  int t = threadIdx.x;
  if (b < BB) {
    f32x4 v = *(const f32x4*)(x + (size_t)b * DD + t * 4);
    u16x4 o;
    float s = 0.f;
#pragma unroll
    for (int j = 0; j < 4; ++j) {
      float f = v[j];
      s += f * f;
      o[j] = f2bf(f);
    }
    *(u16x4*)(xb + (size_t)b * DD + t * 4) = o;
#pragma unroll
    for (int off = 32; off >= 1; off >>= 1) s += __shfl_down(s, off);
    if ((t & 63) == 0) ps[t >> 6] = s;
    __syncthreads();
    if (t == 0) sqx[b] = ps[0] + ps[1] + ps[2] + ps[3];
    return;
  }
  int c = b - BB;
  const float* W;
  unsigned short* Wt;
  int Kd, N, idx;
  if (c < 128)      { W = We1; Wt = Wt1; Kd = DD; N = HH; idx = c; }
  else if (c < 136) { W = We2; Wt = Wt2; Kd = HH; N = LL; idx = c - 128; }
  else if (c < 144) { W = Wd1; Wt = Wt3; Kd = LL; N = HH; idx = c - 136; }
  else              { W = Wd2; Wt = Wt4; Kd = HH; N = DD; idx = c - 144; }
  int nx = Kd >> 6;
  int k0 = (idx % nx) * 64, n0 = (idx / nx) * 64;
  int kr = t >> 4, nc = (t & 15) * 4;
#pragma unroll
  for (int q = 0; q < 4; ++q) {
    int k = kr + q * 16;
    f32x4 v = *(const f32x4*)(W + (size_t)(k0 + k) * N + n0 + nc);
#pragma unroll
    for (int j = 0; j < 4; ++j) T[nc + j][k] = f2bf(v[j]);
  }
  __syncthreads();
#pragma unroll
  for (int q = 0; q < 2; ++q) {
    int s = t + q * 256;
    int n = s >> 3, cc = (s & 7) * 8;
    u16x8 o;
#pragma unroll
    for (int j = 0; j < 8; ++j) o[j] = T[n][cc + j];
    *(u16x8*)(Wt + (size_t)(n0 + n) * Kd + k0 + cc) = o;
  }
}

// ---------------- shared MFMA-GEMM body, 2-phase pipelined k-loop ----------------
template <int NF, int RELU, int FUSE, int STF32, int STBF>
__device__ __forceinline__ void mgemm_body(
    char* LB, int m0, int n0,
    const unsigned short* __restrict__ A, const unsigned short* __restrict__ Wt,
    const float* __restrict__ bias, unsigned short* __restrict__ Cb, float* __restrict__ Cf,
    const float* __restrict__ Xref, float* __restrict__ rec_sum, int N, int Kd) {
  unsigned short* At = (unsigned short*)LB;
  unsigned short* Bt = (unsigned short*)(LB + 16384);
  int t = threadIdx.x;
  int lane = t & 63, w = t >> 6;
  int wr = w >> 1, wc = w & 1;
  int wbase = w * 64;

  const unsigned short* pA[4];
  const unsigned short* pB[NF];
#pragma unroll
  for (int q = 0; q < 4; ++q) {
    int s = q * 256 + t;
    int r = s >> 3, g = s & 7;
    pA[q] = A + (size_t)(m0 + r) * Kd + (g ^ (r & 7)) * 8;
  }
#pragma unroll
  for (int q = 0; q < NF; ++q) {
    int s = q * 256 + t;
    int r = s >> 3, g = s & 7;
    pB[q] = Wt + (size_t)(n0 + r) * Kd + (g ^ (r & 7)) * 8;
  }

  int lrow = lane & 15;
  int klo = (lane >> 4) << 4;
  int sw = (lane & 7) << 4;

  f32x4 acc[4][NF] = {};

  int ksteps = Kd >> 6;
  // prologue: stage step 0
#pragma unroll
  for (int q = 0; q < 4; ++q) { gload16(pA[q], At + (q * 256 + wbase) * 8); pA[q] += 64; }
#pragma unroll
  for (int q = 0; q < NF; ++q) { gload16(pB[q], Bt + (q * 256 + wbase) * 8); pB[q] += 64; }

  for (int kt = 0; kt < ksteps; ++kt) {
    __syncthreads();  // stage(kt) landed (vmcnt drained here, AFTER prev MFMAs)
    fragT af[2][4], bf[2][NF];
#pragma unroll
    for (int kh = 0; kh < 2; ++kh) {
      int kbyte = ((kh << 6) | klo) ^ sw;
#pragma unroll
      for (int m = 0; m < 4; ++m)
        af[kh][m] = *(const fragT*)((const char*)At + (wr * 64 + m * 16 + lrow) * 128 + kbyte);
#pragma unroll
      for (int n = 0; n < NF; ++n)
        bf[kh][n] = *(const fragT*)((const char*)Bt + (wc * NF * 16 + n * 16 + lrow) * 128 + kbyte);
    }
    __syncthreads();  // all waves consumed LDS into regs
    if (kt + 1 < ksteps) {
#pragma unroll
      for (int q = 0; q < 4; ++q) { gload16(pA[q], At + (q * 256 + wbase) * 8); pA[q] += 64; }
#pragma unroll
      for (int q = 0; q < NF; ++q) { gload16(pB[q], Bt + (q * 256 + wbase) * 8); pB[q] += 64; }
    }
#pragma unroll
    for (int kh = 0; kh < 2; ++kh)
#pragma unroll
      for (int m = 0; m < 4; ++m)
#pragma unroll
        for (int n = 0; n < NF; ++n)
          acc[m][n] =
              __builtin_amdgcn_mfma_f32_16x16x32_bf16(af[kh][m], bf[kh][n], acc[m][n], 0, 0, 0);
  }

  float local = 0.f;
#pragma unroll
  for (int m = 0; m < 4; ++m) {
    int row0 = m0 + wr * 64 + m * 16 + ((lane >> 4) << 2);
#pragma unroll
    for (int n = 0; n < NF; ++n) {
      int col = n0 + wc * NF * 16 + n * 16 + lrow;
      float bv = bias[col];
      f32x4 a = acc[m][n];
#pragma unroll
      for (int j = 0; j < 4; ++j) {
        float c = a[j] + bv;
        if (RELU) c = fmaxf(c, 0.f);
        if (FUSE) {
          float xv = Xref[(size_t)(row0 + j) * N + col];
          float d = c - xv;
          local = fmaf(d, d, local);
        }
        if (STBF) Cb[(size_t)(row0 + j) * N + col] = f2bf(c);
        if (STF32) Cf[(size_t)(row0 + j) * N + col] = c;
      }
    }
  }
  if (FUSE) {
#pragma unroll
    for (int off = 32; off >= 1; off >>= 1) local += __shfl_down(local, off);
    __shared__ float rs[4];
    if ((t & 63) == 0) rs[t >> 6] = local;
    __syncthreads();
    if (t == 0) atomicAdd(rec_sum, rs[0] + rs[1] + rs[2] + rs[3]);
  }
}

// ---------------- standalone MFMA GEMM ----------------
template <int NF, int RELU, int FUSE, int STF32, int STBF>
__global__ __launch_bounds__(256) void k_mgemm(
    const unsigned short* __restrict__ A, const unsigned short* __restrict__ Wt,
    const float* __restrict__ bias, unsigned short* __restrict__ Cb, float* __restrict__ Cf,
    const float* __restrict__ Xref, float* __restrict__ rec_sum, int N, int Kd) {
  __shared__ __attribute__((aligned(16))) char LB[16384 + NF * 32 * 128];
  mgemm_body<NF, RELU, FUSE, STF32, STBF>(LB, blockIdx.y * 128, blockIdx.x * (NF * 32),
                                          A, Wt, bias, Cb, Cf, Xref, rec_sum, N, Kd);
}

// ---------------- fat kernel: G1 (first 256 blocks) + Gram/top-15 ----------------
__global__ __launch_bounds__(256, 3) void k_gram_topk(
    const unsigned short* __restrict__ xb, const float* __restrict__ sqx,
    unsigned* __restrict__ part,
    const unsigned short* __restrict__ Wt1, const float* __restrict__ be1,
    unsigned short* __restrict__ hb) {
  __shared__ __attribute__((aligned(16))) char LB[33792];

  int bid0 = blockIdx.x;
  if (bid0 < NG1) {
    mgemm_body<4, 1, 0, 0, 1>(LB, (bid0 >> 2) * 128, (bid0 & 3) * 128,
                              xb, Wt1, be1, hb, nullptr, nullptr, nullptr, HH, DD);
    return;
  }

  unsigned short* At = (unsigned short*)LB;
  unsigned short* Bt = (unsigned short*)(LB + 16384);
  char* Sf = LB;                                  // scan phase (overlays At)
  unsigned* scratch = (unsigned*)(LB + 16384);    // scan phase (overlays Bt)
  float* sqr = (float*)(LB + 32768);
  float* sqc = (float*)(LB + 33280);

  int g = bid0 - NG1;
  int k = g & 7, m = g >> 3;
  int nA = 6 + 4 * (61 - 4 * k);
  int b, mm;
  if (m < nA) { b = k; mm = m; }
  else        { b = 15 - k; mm = m - nA; }
  int ctl, j;
  if (mm < 6) {
    if (mm < 1)      { ctl = 0; j = mm; }
    else if (mm < 3) { ctl = 1; j = mm - 1; }
    else             { ctl = 2; j = mm - 3; }
  } else {
    ctl = 3 + ((mm - 6) >> 2);
    j = (mm - 6) & 3;
  }
  int rt = 4 * b + j;
  int ct = 4 * b + ctl;
  bool diag = (rt == ct);
  int r0 = rt * 128, c0 = ct * 128;

  int t = threadIdx.x;
  int lane = t & 63, w = t >> 6;
  int wr = w >> 1, wc = w & 1;
  int wbase = w * 64;

  if (t < 128) {
    sqr[t] = sqx[r0 + t];
    sqc[t] = sqx[c0 + t];
  }

  const unsigned short* pA[4];
  const unsigned short* pB[4];
#pragma unroll
  for (int q = 0; q < 4; ++q) {
    int s = q * 256 + t;
    int r = s >> 3, gg = s & 7;
    int kk = (gg ^ (r & 7)) * 8;
    pA[q] = xb + (size_t)(r0 + r) * DD + kk;
    pB[q] = xb + (size_t)(c0 + r) * DD + kk;
  }

  int lrow = lane & 15;
  int klo = (lane >> 4) << 4;
  int sw = (lane & 7) << 4;

  f32x4 acc[16] = {};

  // prologue: stage step 0
#pragma unroll
  for (int q = 0; q < 4; ++q) {
    gload16(pA[q], At + (q * 256 + wbase) * 8); pA[q] += 64;
    gload16(pB[q], Bt + (q * 256 + wbase) * 8); pB[q] += 64;
  }

  for (int kt = 0; kt < 16; ++kt) {
    __syncthreads();  // stage(kt) landed
    fragT af[2][4], bf[2][4];
#pragma unroll
    for (int kh = 0; kh < 2; ++kh) {
      int kbyte = ((kh << 6) | klo) ^ sw;
#pragma unroll
      for (int mq = 0; mq < 4; ++mq)
        af[kh][mq] = *(const fragT*)((const char*)At + (wr * 64 + mq * 16 + lrow) * 128 + kbyte);
#pragma unroll
      for (int n = 0; n < 4; ++n)
        bf[kh][n] = *(const fragT*)((const char*)Bt + (wc * 64 + n * 16 + lrow) * 128 + kbyte);
    }
    __syncthreads();  // all waves consumed LDS
    if (kt < 15) {
#pragma unroll
      for (int q = 0; q < 4; ++q) {
        gload16(pA[q], At + (q * 256 + wbase) * 8); pA[q] += 64;
        gload16(pB[q], Bt + (q * 256 + wbase) * 8); pB[q] += 64;
      }
    }
#pragma unroll
    for (int kh = 0; kh < 2; ++kh)
#pragma unroll
      for (int mq = 0; mq < 4; ++mq)
#pragma unroll
        for (int n = 0; n < 4; ++n)
          acc[mq * 4 + n] = __builtin_amdgcn_mfma_f32_16x16x32_bf16(af[kh][mq], bf[kh][n],
                                                                   acc[mq * 4 + n], 0, 0, 0);
  }

  unsigned rowlist[KNN];
#pragma unroll
  for (int p = 0; p < KNN; ++p) rowlist[p] = 0xFFFFFFFFu;

  int scanrow = t & 127, side = t >> 7;

#pragma unroll
  for (int nh = 0; nh < 2; ++nh) {
    // write d2 half-tile to swizzled f16 Sf (overlays A-stage)
    if (wc == nh) {
#pragma unroll
      for (int mq = 0; mq < 4; ++mq) {
        int row0 = wr * 64 + mq * 16 + ((lane >> 4) << 2);
        f32x4 sq4 = *(const f32x4*)&sqr[row0];
#pragma unroll
        for (int n = 0; n < 4; ++n) {
          int colL = n * 16 + lrow;
          float sc = sqc[nh * 64 + colL];
          f32x4 a = acc[mq * 4 + n];
          f16x4 hv;
#pragma unroll
          for (int r = 0; r < 4; ++r) {
            float d2 = fmaxf(sq4[r] + sc - 2.f * a[r], 0.f);
            if (diag && (row0 + r == nh * 64 + colL)) d2 = 60000.f;
            hv[r] = (_Float16)d2;
          }
          *(f16x4*)(Sf + colL * 256 + (((row0 * 2)) ^ ((colL & 31) << 3))) = hv;
        }
      }
    }
    __syncthreads();
    // row-scan: 2 threads/row, 32 cols each; chunk-of-4 min prefilter
    {
      int cbase = side * 32;
      int jbase = c0 + nh * 64;
      for (int cc = 0; cc < 32; cc += 4) {
        unsigned u[4];
#pragma unroll
        for (int q = 0; q < 4; ++q) {
          int colL = cbase + cc + q;
          unsigned bits = *(const unsigned short*)(Sf + colL * 256 +
                                                   ((scanrow * 2) ^ ((colL & 31) << 3)));
          u[q] = (bits << 16) | (unsigned)(jbase + colL);
        }
        unsigned m4 = min(min(u[0], u[1]), min(u[2], u[3]));
        if (m4 < rowlist[KNN - 1]) {
#pragma unroll
          for (int q = 0; q < 4; ++q) ins15(rowlist, u[q]);
        }
      }
    }
    // col-scan: b64 loads of 4 consecutive rows + min prefilter
    if (!diag) {
      int c = t & 63, seg = t >> 6;
      unsigned collist[KNN];
#pragma unroll
      for (int p = 0; p < KNN; ++p) collist[p] = 0xFFFFFFFFu;
      for (int rq = 0; rq < 8; ++rq) {
        int r = seg * 32 + rq * 4;
        u16x4 v4 = *(const u16x4*)(Sf + c * 256 + ((r * 2) ^ ((c & 31) << 3)));
        unsigned u[4];
#pragma unroll
        for (int jj = 0; jj < 4; ++jj) u[jj] = ((unsigned)v4[jj] << 16) | (unsigned)(r0 + r + jj);
        unsigned m4 = min(min(u[0], u[1]), min(u[2], u[3]));
        if (m4 < collist[KNN - 1]) {
#pragma unroll
          for (int jj = 0; jj < 4; ++jj) ins15(collist, u[jj]);
        }
      }
      __syncthreads();
#pragma unroll
      for (int p = 0; p < KNN; ++p) scratch[(c * 4 + seg) * KNN + p] = collist[p];
      __syncthreads();
      if (t < 64) {
        unsigned fin[KNN];
#pragma unroll
        for (int p = 0; p < KNN; ++p) fin[p] = 0xFFFFFFFFu;
        for (int s = 0; s < 4; ++s)
#pragma unroll
          for (int p = 0; p < KNN; ++p) ins15(fin, scratch[(t * 4 + s) * KNN + p]);
        int jj = c0 + nh * 64 + t;
#pragma unroll
        for (int p = 0; p < KNN; ++p) part[((size_t)(rt * KNN + p)) * BB + jj] = fin[p];
      }
    }
    __syncthreads();
  }

  // merge the 2 per-side row lists, write slot ct
#pragma unroll
  for (int p = 0; p < KNN; ++p) scratch[(scanrow * 2 + side) * KNN + p] = rowlist[p];
  __syncthreads();
  if (t < 128) {
    unsigned fin[KNN];
#pragma unroll
    for (int p = 0; p < KNN; ++p) fin[p] = 0xFFFFFFFFu;
    for (int s = 0; s < 2; ++s)
#pragma unroll
      for (int p = 0; p < KNN; ++p) ins15(fin, scratch[(t * 2 + s) * KNN + p]);
    int i = r0 + t;
#pragma unroll
    for (int p = 0; p < KNN; ++p) part[((size_t)(ct * KNN + p)) * BB + i] = fin[p];
  }
}

// ---------------- merge stage 1: 64 slots -> 4, early-exit on sorted slots ----------------
__global__ void k_merge1(const unsigned* __restrict__ part, unsigned* __restrict__ part2) {
  int gid = blockIdx.x * 256 + threadIdx.x;  // 32768
  int s = gid >> 13, i = gid & 8191;
  unsigned l[KNN];
#pragma unroll
  for (int p = 0; p < KNN; ++p) l[p] = 0xFFFFFFFFu;
  for (int b = s * 16; b < s * 16 + 16; ++b) {
    size_t base = (size_t)(b * KNN) * BB + i;
    unsigned u = part[base];
    if (u < l[KNN - 1]) {
      ins15(l, u);
      for (int p = 1; p < KNN; ++p) {
        u = part[base + (size_t)p * BB];
        if (u >= l[KNN - 1]) break;
        ins15(l, u);
      }
    }
  }
#pragma unroll
  for (int p = 0; p < KNN; ++p) part2[((size_t)(s * KNN + p)) * BB + i] = l[p];
}

// ---------------- merge stage 2: final top-15 + xmax ----------------
__global__ void k_merge2(const unsigned* __restrict__ part2, float* __restrict__ knn_d2,
                         int* __restrict__ knn_idx, int* __restrict__ xmax_bits) {
  int i = blockIdx.x * 256 + threadIdx.x;
  unsigned l[KNN];
#pragma unroll
  for (int p = 0; p < KNN; ++p) l[p] = 0xFFFFFFFFu;
  for (int q = 0; q < 4; ++q) {
    size_t base = (size_t)(q * KNN) * BB + i;
    unsigned u = part2[base];
    if (u < l[KNN - 1]) {
      ins15(l, u);
      for (int p = 1; p < KNN; ++p) {
        u = part2[base + (size_t)p * BB];
        if (u >= l[KNN - 1]) break;
        ins15(l, u);
      }
    }
  }
  float mx = 0.f;
#pragma unroll
  for (int p = 0; p < KNN; ++p) {
    unsigned u = l[p];
    float d = fmaxf(unpack_d2(u), 0.f);
    mx = fmaxf(mx, d);
    knn_d2[(size_t)i * KNN + p] = d;
    knn_idx[(size_t)i * KNN + p] = (int)(u & 0xFFFFu);
  }
  int t = threadIdx.x;
#pragma unroll
  for (int off = 32; off >= 1; off >>= 1) mx = fmaxf(mx, __shfl_down(mx, off));
  __shared__ float rm[4];
  if ((t & 63) == 0) rm[t >> 6] = mx;
  __syncthreads();
  if (t == 0) {
    float mb = fmaxf(fmaxf(rm[0], rm[1]), fmaxf(rm[2], rm[3]));
    atomicMax(xmax_bits, __float_as_int(mb));
  }
}

// ---------------- fused edge kernel: zd2 + reciprocity + partial sums ----------------
__global__ void k_edge(const float* __restrict__ z, const int* __restrict__ knn_idx,
                       const float* __restrict__ knn_d2, float* __restrict__ pzz,
                       float* __restrict__ pxx, float* __restrict__ pxz,
                       float* __restrict__ pcnt, float* __restrict__ pzm) {
  int t = threadIdx.x;
  int g = t >> 4, L = t & 15;
  int lane = t & 63;
  float szz = 0.f, sxx = 0.f, sxz = 0.f, scnt = 0.f, zm = 0.f;
#pragma unroll
  for (int pass = 0; pass < 8; ++pass) {
    int e = blockIdx.x * 128 + pass * 16 + g;
    int i = e / KNN;
    int j = knn_idx[e];
    f32x4 zi = *(const f32x4*)(z + (size_t)i * LL + L * 4);
    f32x4 zj = *(const f32x4*)(z + (size_t)j * LL + L * 4);
    float v = 0.f;
#pragma unroll
    for (int d = 0; d < 4; ++d) {
      float df = zi[d] - zj[d];
      v = fmaf(df, df, v);
    }
    v += __shfl_down(v, 8);
    v += __shfl_down(v, 4);
    v += __shfl_down(v, 2);
    v += __shfl_down(v, 1);
    int cand = (L < KNN) ? knn_idx[(size_t)j * KNN + L] : -1;
    unsigned long long ball = __ballot(cand == i);
    unsigned recip = (unsigned)(ball >> (lane & 48)) & 0xFFFFu;
    if (L == 0) {
      float w = recip ? 1.f : 2.f;
      float xd2 = knn_d2[e];
      szz = fmaf(w, v, szz);
      sxx = fmaf(w, xd2, sxx);
      sxz = fmaf(w, sqrtf(v * xd2), sxz);
      scnt += w;
      zm = fmaxf(zm, v);
    }
  }
#pragma unroll
  for (int off = 32; off >= 1; off >>= 1) {
    szz += __shfl_down(szz, off);
    sxx += __shfl_down(sxx, off);
    sxz += __shfl_down(sxz, off);
    scnt += __shfl_down(scnt, off);
    zm = fmaxf(zm, __shfl_down(zm, off));
  }
  __shared__ float r[5][4];
  int w4 = t >> 6;
  if (lane == 0) {
    r[0][w4] = szz; r[1][w4] = sxx; r[2][w4] = sxz; r[3][w4] = scnt; r[4][w4] = zm;
  }
  __syncthreads();
  if (t == 0) {
    pzz[blockIdx.x] = r[0][0] + r[0][1] + r[0][2] + r[0][3];
    pxx[blockIdx.x] = r[1][0] + r[1][1] + r[1][2] + r[1][3];
    pxz[blockIdx.x] = r[2][0] + r[2][1] + r[2][2] + r[2][3];
    pcnt[blockIdx.x] = r[3][0] + r[3][1] + r[3][2] + r[3][3];
    pzm[blockIdx.x] = fmaxf(fmaxf(r[4][0], r[4][1]), fmaxf(r[4][2], r[4][3]));
  }
}

// ---------------- final: reduce partials, assemble scalar loss ----------------
__global__ void k_final(const float* __restrict__ pzz, const float* __restrict__ pxx,
                        const float* __restrict__ pxz, const float* __restrict__ pcnt,
                        const float* __restrict__ pzm, const int* __restrict__ xmax_bits,
                        const float* __restrict__ rec_sum, float* __restrict__ out) {
  int t = threadIdx.x;
  float szz = 0.f, sxx = 0.f, sxz = 0.f, scnt = 0.f, zm = 0.f;
  for (int bb = t; bb < NEBLK; bb += 256) {
    szz += pzz[bb];
    sxx += pxx[bb];
    sxz += pxz[bb];
    scnt += pcnt[bb];
    zm = fmaxf(zm, pzm[bb]);
  }
#pragma unroll
  for (int off = 32; off >= 1; off >>= 1) {
    szz += __shfl_down(szz, off);
    sxx += __shfl_down(sxx, off);
    sxz += __shfl_down(sxz, off);
    scnt += __shfl_down(scnt, off);
    zm = fmaxf(zm, __shfl_down(zm, off));
  }
  __shared__ float r[5][4];
  int w4 = t >> 6;
  if ((t & 63) == 0) {
    r[0][w4] = szz; r[1][w4] = sxx; r[2][w4] = sxz; r[3][w4] = scnt; r[4][w4] = zm;
  }
  __syncthreads();
  if (t == 0) {
    float SZZ = r[0][0] + r[0][1] + r[0][2] + r[0][3];
    float SXX = r[1][0] + r[1][1] + r[1][2] + r[1][3];
    float SXZ = r[2][0] + r[2][1] + r[2][2] + r[2][3];
    float CNT = r[3][0] + r[3][1] + r[3][2] + r[3][3];
    float ZM = fmaxf(fmaxf(r[4][0], r[4][1]), fmaxf(r[4][2], r[4][3]));
    float xmax = __int_as_float(*xmax_bits);
    float a = 1.f / (sqrtf(ZM) + 1e-8f);
    float bq = 1.f / (sqrtf(xmax) + 1e-8f);
    float loss = (a * a * SZZ + bq * bq * SXX - 2.f * a * bq * SXZ) / CNT;
    out[0] = rec_sum[0] * (1.f / 8388608.f) + loss;
  }
}

extern "C" void kernel_launch(void* const* d_in, const int* in_sizes, int n_in,
                              void* d_out, int out_size, void* d_ws, size_t ws_size,
                              hipStream_t stream) {
  const float* x = (const float*)d_in[0];
  const float* We1 = (const float*)d_in[1];
  const float* be1 = (const float*)d_in[2];
  const float* We2 = (const float*)d_in[3];
  const float* be2 = (const float*)d_in[4];
  const float* Wd1 = (const float*)d_in[5];
  const float* bd1 = (const float*)d_in[6];
  const float* Wd2 = (const float*)d_in[7];
  const float* bd2 = (const float*)d_in[8];

  char* ws = (char*)d_ws;
  size_t off = 0;
  auto alloc = [&](size_t bytes) {
    void* p = ws + off;
    off += (bytes + 255) & ~(size_t)255;
    return p;
  };
  unsigned short* xb = (unsigned short*)alloc((size_t)BB * DD * 2);
  unsigned short* hb = (unsigned short*)alloc((size_t)BB * HH * 2);
  unsigned short* zb = (unsigned short*)alloc((size_t)BB * LL * 2);
  unsigned short* h2b = (unsigned short*)alloc((size_t)BB * HH * 2);
  float* z = (float*)alloc((size_t)BB * LL * 4);
  float* sqx = (float*)alloc((size_t)BB * 4);
  unsigned short* Wt1 = (unsigned short*)alloc((size_t)HH * DD * 2);
  unsigned short* Wt2 = (unsigned short*)alloc((size_t)LL * HH * 2);
  unsigned short* Wt3 = (unsigned short*)alloc((size_t)HH * LL * 2);
  unsigned short* Wt4 = (unsigned short*)alloc((size_t)DD * HH * 2);
  unsigned* part = (unsigned*)alloc((size_t)NT * KNN * BB * 4);   // 31.5MB
  unsigned* part2 = (unsigned*)alloc((size_t)4 * KNN * BB * 4);   // 2MB
  float* knn_d2 = (float*)alloc((size_t)BB * KNN * 4);
  int* knn_idx = (int*)alloc((size_t)BB * KNN * 4);
  float* pzz = (float*)alloc(NEBLK * 4);
  float* pxx = (float*)alloc(NEBLK * 4);
  float* pxz = (float*)alloc(NEBLK * 4);
  float* pcnt = (float*)alloc(NEBLK * 4);
  float* pzm = (float*)alloc(NEBLK * 4);
  float* scal = (float*)alloc(64);
  float* rec_sum = scal + 0;
  int* xmax_bits = (int*)(scal + 1);

  hipMemsetAsync(scal, 0, 64, stream);

  k_prep<<<BB + 272, 256, 0, stream>>>(x, xb, sqx, We1, We2, Wd1, Wd2, Wt1, Wt2, Wt3, Wt4);

  // fat kernel: G1 (256 blocks) + gram/top-15 (2080 blocks)
  k_gram_topk<<<NG1 + NTILES, 256, 0, stream>>>(xb, sqx, part, Wt1, be1, hb);

  k_mgemm<2, 0, 0, 1, 1><<<dim3(LL / 64, BB / 128), 256, 0, stream>>>(
      hb, Wt2, be2, zb, z, nullptr, nullptr, LL, HH);
  k_mgemm<4, 1, 0, 0, 1><<<dim3(HH / 128, BB / 128), 256, 0, stream>>>(
      zb, Wt3, bd1, h2b, nullptr, nullptr, nullptr, HH, LL);
  k_mgemm<4, 0, 1, 0, 0><<<dim3(DD / 128, BB / 128), 256, 0, stream>>>(
      h2b, Wt4, bd2, nullptr, nullptr, x, rec_sum, DD, HH);

  k_merge1<<<128, 256, 0, stream>>>(part, part2);
  k_merge2<<<BB / 256, 256, 0, stream>>>(part2, knn_d2, knn_idx, xmax_bits);
  k_edge<<<NEBLK, 256, 0, stream>>>(z, knn_idx, knn_d2, pzz, pxx, pxz, pcnt, pzm);
  k_final<<<1, 256, 0, stream>>>(pzz, pxx, pxz, pcnt, pzm, xmax_bits, rec_sum, (float*)d_out);
}